// Round 12
// baseline (698.777 us; speedup 1.0000x reference)
//
#include <hip/hip_runtime.h>
#include <math.h>

// ---------------------------------------------------------------------------
// TannerGNN. Round 12: k_msg = exact R9 core (best measured: 89us) + compact
// LDS: sMsg (f32) processed in two 64-col passes aliasing the dead sHid
// buffer. 76.5 -> 43.5 KB => 3 blocks/CU (24 waves, was 16). Reduction
// strips 8x16 (boundaries superset of R9's; same in-run order). Everything
// else unchanged from R11/R9.
// N_NODES=50000, N_EDGES=400000, H=128, L=3, T=2, FEAT=4, N_DATA=40000.
// ---------------------------------------------------------------------------

#define H 128
#define TE2 128        // edges per message block
#define MSH 68         // sMsg half-row stride in f32 (64 cols + 4 pad)
#define HS  136        // sHid/sIn row stride in bf16
#define FEAT 4
#define WG_PER_LAYER 196608   // 2 mat * 2 split * 4 kc * 24 jtg * 64 lane * 8

typedef __bf16 bf16x8 __attribute__((ext_vector_type(8)));
typedef __bf16 bf16x4 __attribute__((ext_vector_type(4)));
typedef float  f32x4  __attribute__((ext_vector_type(4)));

// ---------------- input projection: h = relu(x @ W_in + b_in) --------------
__global__ __launch_bounds__(256) void k_input(
    const float* __restrict__ x, const float* __restrict__ Win,
    const float* __restrict__ bin, float* __restrict__ h,
    __bf16* __restrict__ hb, int n_nodes)
{
    int idx = blockIdx.x * 256 + threadIdx.x;
    if (idx >= n_nodes * H) return;
    int n = idx >> 7, j = idx & 127;
    float acc = bin[j];
#pragma unroll
    for (int f = 0; f < FEAT; f++)
        acc += x[n * FEAT + f] * Win[f * H + j];
    float v = fmaxf(acc, 0.f);
    h[idx] = v;
    hb[idx] = (__bf16)v;
}

// ---------------- message-weight conversion: bf16, MFMA-fragment order -----
__global__ __launch_bounds__(256) void k_wconv(
    const float* __restrict__ W1, const float* __restrict__ W2,
    __bf16* __restrict__ Wsw)
{
    int gid = blockIdx.x * 256 + threadIdx.x;
    const int per_lt = 12 * 4096;
    if (gid >= 6 * per_lt) return;
    int lt = gid / per_lt, rem = gid % per_lt;
    int chunk = rem >> 12;
    int within = rem & 4095;
    int ct = within >> 9;
    int lane = (within >> 3) & 63;
    int j = within & 7;
    int r = lane & 15, quad = lane >> 4;
    int n = ct * 16 + r;
    float v;
    if (chunk < 8) {
        int k = chunk * 32 + quad * 8 + j;
        v = W1[((size_t)lt * 256 + k) * 128 + n];
    } else {
        int k = (chunk - 8) * 32 + quad * 8 + j;
        v = W2[((size_t)lt * 128 + k) * 128 + n];
    }
    Wsw[gid] = (__bf16)v;
}

// ---------------- GRU-weight conversion: hi/lo split, B-fragment order -----
__global__ __launch_bounds__(256) void k_wgconv(
    const float* __restrict__ Wih, const float* __restrict__ Whh,
    __bf16* __restrict__ Wg)
{
    int gid = blockIdx.x * 256 + threadIdx.x;
    if (gid >= 3 * WG_PER_LAYER) return;
    int layer = gid / WG_PER_LAYER, rem = gid % WG_PER_LAYER;
    int t = rem & 7;
    int lane = (rem >> 3) & 63;
    int jtg = (rem >> 9) % 24;
    int mk = rem / 12288;          // (mat*2+split)*4 + kc, 0..15
    int kc = mk & 3;
    int msplit = mk >> 2;          // 0..3
    int mat = msplit >> 1, split = msplit & 1;
    int r = lane & 15, quad = lane >> 4;
    int k = kc * 32 + quad * 8 + t;
    int n = jtg * 16 + r;
    const float* W = (mat ? Whh : Wih) + (size_t)layer * 128 * 384;
    float v = W[(size_t)k * 384 + n];
    __bf16 hi = (__bf16)v;
    Wg[gid] = split ? (__bf16)(v - (float)hi) : hi;
}

// ---------------- counting sort by key = type*nn + dst ---------------------
__global__ __launch_bounds__(256) void k_hist(
    const int* __restrict__ et, const int* __restrict__ dst,
    int* __restrict__ cnt, int n_edges, int nn)
{
    int i = blockIdx.x * 256 + threadIdx.x;
    if (i < n_edges) atomicAdd(&cnt[et[i] * nn + dst[i]], 1);
}

__global__ __launch_bounds__(1024) void k_scan1(
    const int* __restrict__ cnt, int* __restrict__ bsum, int n)
{
    int i = blockIdx.x * 1024 + threadIdx.x;
    int v = (i < n) ? cnt[i] : 0;
#pragma unroll
    for (int off = 32; off > 0; off >>= 1) v += __shfl_down(v, off, 64);
    __shared__ int ws[16];
    int lane = threadIdx.x & 63, w = threadIdx.x >> 6;
    if (lane == 0) ws[w] = v;
    __syncthreads();
    if (threadIdx.x < 16) {
        int x = ws[threadIdx.x];
#pragma unroll
        for (int off = 8; off > 0; off >>= 1) x += __shfl_down(x, off, 64);
        if (threadIdx.x == 0) bsum[blockIdx.x] = x;
    }
}

__global__ __launch_bounds__(128) void k_scan2(
    int* __restrict__ bsum, int* __restrict__ offs, int nb, int n)
{
    int lane = threadIdx.x & 63, w = threadIdx.x >> 6;
    int v = (threadIdx.x < nb) ? bsum[threadIdx.x] : 0;
    int orig = v;
#pragma unroll
    for (int off = 1; off < 64; off <<= 1) {
        int t = __shfl_up(v, off, 64);
        if (lane >= off) v += t;
    }
    __shared__ int w0sum;
    if (threadIdx.x == 63) w0sum = v;
    __syncthreads();
    int ex = v - orig + (w ? w0sum : 0);
    if (threadIdx.x < nb) bsum[threadIdx.x] = ex;
    if (threadIdx.x == nb - 1) offs[n] = ex + orig;
}

__global__ __launch_bounds__(1024) void k_scan3(
    const int* __restrict__ cnt, const int* __restrict__ bsum,
    int* __restrict__ offs, int n)
{
    int i = blockIdx.x * 1024 + threadIdx.x;
    int v = (i < n) ? cnt[i] : 0;
    int orig = v;
    int lane = threadIdx.x & 63, w = threadIdx.x >> 6;
#pragma unroll
    for (int off = 1; off < 64; off <<= 1) {
        int t = __shfl_up(v, off, 64);
        if (lane >= off) v += t;
    }
    __shared__ int ws[16];
    if (lane == 63) ws[w] = v;
    __syncthreads();
    if (threadIdx.x < 16) {
        int x = ws[threadIdx.x];
#pragma unroll
        for (int off = 1; off < 16; off <<= 1) {
            int t = __shfl_up(x, off, 64);
            if (lane >= off) x += t;
        }
        ws[threadIdx.x] = x;
    }
    __syncthreads();
    int wbase = w ? ws[w - 1] : 0;
    if (i < n) offs[i] = bsum[blockIdx.x] + wbase + v - orig;
}

__global__ __launch_bounds__(256) void k_place(
    const int* __restrict__ et, const int* __restrict__ dst,
    const int* __restrict__ offs, int* __restrict__ cnt,
    int* __restrict__ bucket, int n_edges, int nn)
{
    int i = blockIdx.x * 256 + threadIdx.x;
    if (i < n_edges) {
        int key = et[i] * nn + dst[i];
        int p = atomicAdd(&cnt[key], -1) - 1;
        bucket[offs[key] + p] = i;
    }
}

// ---------------- fused MFMA message kernel (R9 core, compact LDS) ---------
// Block = 128 dst-sorted edges of one type, 8 waves; wave w owns 16 edges.
// Transposed MFMA (A=weight frag from LDS, B=edge frag in regs). Phase C in
// two 64-col passes, sMsg aliasing the dead sHid buffer: 43.5 KB LDS total
// -> 3 blocks/CU.
__global__ __launch_bounds__(512, 6) void k_msg(
    const __bf16* __restrict__ hb,
    const int* __restrict__ bucket, const int* __restrict__ offs,
    const int* __restrict__ src, const int* __restrict__ dst,
    const __bf16* __restrict__ Wsw, const float* __restrict__ b1l,
    const float* __restrict__ b2l,
    float* __restrict__ agg, int n_edges, int nn)
{
    const int t = blockIdx.y;
    const int c0 = offs[nn];
    const int cnt = t ? (n_edges - c0) : c0;
    const int base = t ? c0 : 0;
    const int start = blockIdx.x * TE2;
    if (start >= cnt) return;

    const __bf16* __restrict__ W = Wsw + (size_t)t * 12 * 4096;
    const float*  __restrict__ b1 = b1l + t * H;
    const float*  __restrict__ b2 = b2l + t * H;

    __shared__ __bf16 sW[4096];            // 8 KB weight chunk
    __shared__ __bf16 sBuf[TE2 * HS];      // 34816 B: sHid, then sMsg halves
    __shared__ int    sDstV[TE2];
    __bf16* sHid = sBuf;                   // row = edge, stride HS bf16
    float*  sMsg = (float*)sBuf;           // row = edge, stride MSH f32

    const int tid  = threadIdx.x;
    const int lane = tid & 63;
    const int w    = tid >> 6;
    const int r    = lane & 15;
    const int quad = lane >> 4;

    f32x4 wreg[12];
#pragma unroll
    for (int c = 0; c < 12; c++)
        wreg[c] = *(const f32x4*)(W + c * 4096 + tid * 8);

    if (tid < TE2) {
        int i = start + tid;
        sDstV[tid] = (i < cnt) ? dst[bucket[base + i]] : -1;
    }

    int ei = start + w * 16 + r;
    int e = bucket[base + (ei < cnt ? ei : cnt - 1)];
    const __bf16* aps = hb + (size_t)src[e] * H;
    const __bf16* apd = hb + (size_t)dst[e] * H;

    bf16x8 afS[4];
#pragma unroll
    for (int i = 0; i < 4; i++)
        afS[i] = *(const bf16x8*)(aps + i * 32 + quad * 8);

    __syncthreads();

    // ---- Phase A: hidT = (cat @ W1)^T, K=256 in 8 chunks ----
    f32x4 acc[8];
#pragma unroll
    for (int ct = 0; ct < 8; ct++) acc[ct] = (f32x4){0.f, 0.f, 0.f, 0.f};

    bf16x8 afD[4];
#pragma unroll
    for (int kc = 0; kc < 8; kc++) {
        __syncthreads();
        *(f32x4*)(sW + tid * 8) = wreg[kc];
        __syncthreads();
        if (kc == 2) {
#pragma unroll
            for (int i = 0; i < 4; i++)
                afD[i] = *(const bf16x8*)(apd + i * 32 + quad * 8);
        }
        bf16x8 b = (kc < 4) ? afS[kc] : afD[kc - 4];
#pragma unroll
        for (int ct = 0; ct < 8; ct++) {
            bf16x8 a = *(const bf16x8*)(sW + ct * 512 + lane * 8);
            acc[ct] = __builtin_amdgcn_mfma_f32_16x16x32_bf16(a, b, acc[ct], 0, 0, 0);
        }
    }

    // epilogue A: bias + relu -> bf16 -> sHid[edge = 16w+r][feat]
#pragma unroll
    for (int ct = 0; ct < 8; ct++) {
        f32x4 bb4 = *(const f32x4*)(b1 + ct * 16 + quad * 4);
        bf16x4 hv;
#pragma unroll
        for (int g = 0; g < 4; g++)
            hv[g] = (__bf16)fmaxf(acc[ct][g] + bb4[g], 0.f);
        *(bf16x4*)(sHid + (w * 16 + r) * HS + ct * 16 + quad * 4) = hv;
    }

    // ---- Phase B: msgT = (hid @ W2)^T, K=128 in 4 chunks ----
    f32x4 acc2[8];
#pragma unroll
    for (int ct = 0; ct < 8; ct++) acc2[ct] = (f32x4){0.f, 0.f, 0.f, 0.f};
#pragma unroll
    for (int kc = 0; kc < 4; kc++) {
        __syncthreads();          // orders epilogue-A writes + sW staging
        *(f32x4*)(sW + tid * 8) = wreg[8 + kc];
        __syncthreads();
        bf16x8 b = *(const bf16x8*)(sHid + (w * 16 + r) * HS + kc * 32 + quad * 8);
#pragma unroll
        for (int ct = 0; ct < 8; ct++) {
            bf16x8 a = *(const bf16x8*)(sW + ct * 512 + lane * 8);
            acc2[ct] = __builtin_amdgcn_mfma_f32_16x16x32_bf16(a, b, acc2[ct], 0, 0, 0);
        }
    }

    // ---- Phase C: two 64-col passes; sMsg aliases sHid (own-wave rows
    // only in both Phase B reads and pass writes => no extra hazard).
#pragma unroll
    for (int p = 0; p < 2; p++) {
#pragma unroll
        for (int c = 0; c < 4; c++) {
            int ct = p * 4 + c;
            f32x4 bb4 = *(const f32x4*)(b2 + ct * 16 + quad * 4);
            f32x4 mv;
#pragma unroll
            for (int g = 0; g < 4; g++)
                mv[g] = acc2[ct][g] + bb4[g];
            *(f32x4*)(sMsg + (w * 16 + r) * MSH + c * 16 + quad * 4) = mv;
        }
        __syncthreads();
        // segmented reduction: 8 strips x 16 edges, 64 cols of this pass
        {
            int j = tid & 63, strip = tid >> 6;
            int jcol = p * 64 + j;
            int e0 = strip * 16;
            float run = 0.f; int curd = -1;
            for (int qq = 0; qq < 16; qq++) {
                int d = sDstV[e0 + qq];
                float v = sMsg[(e0 + qq) * MSH + j];
                if (d != curd) {
                    if (curd >= 0) atomicAdd(agg + (size_t)curd * H + jcol, run);
                    run = 0.f; curd = d;
                }
                if (d >= 0) run += v;
            }
            if (curd >= 0) atomicAdd(agg + (size_t)curd * H + jcol, run);
        }
        __syncthreads();   // reduction reads done before next pass overwrites
    }
}

// ---------------- GRU cell: split-precision MFMA, double-buffered B --------
// Also zeroes agg (for the next layer) after reading it.
__global__ __launch_bounds__(512, 2) void k_gru(
    float* __restrict__ h, __bf16* __restrict__ hb,
    float* __restrict__ agg,
    const __bf16* __restrict__ Wg,
    const float* __restrict__ bih, const float* __restrict__ bhh,
    int n_nodes)
{
    const int nb = blockIdx.x * 32;
    const int tid = threadIdx.x;
    __shared__ __bf16 sIn[4][32][HS];   // agg_hi, agg_lo, h_hi, h_lo (34.8 KB)

#pragma unroll
    for (int v = 0; v < 2; v++) {
        int idx = tid + 512 * v;
        int e = idx >> 5, c4 = (idx & 31) * 4;
        int n = nb + e;
        float4 av = {0.f, 0.f, 0.f, 0.f}, hv = {0.f, 0.f, 0.f, 0.f};
        if (n < n_nodes) {
            av = *(const float4*)(agg + (size_t)n * H + c4);
            hv = *(const float4*)(h + (size_t)n * H + c4);
            float4 z = {0.f, 0.f, 0.f, 0.f};
            *(float4*)(agg + (size_t)n * H + c4) = z;   // ready for next layer
        }
        bf16x4 ahi, alo, hhi, hlo;
        float af[4] = {av.x, av.y, av.z, av.w};
        float hf[4] = {hv.x, hv.y, hv.z, hv.w};
#pragma unroll
        for (int c = 0; c < 4; c++) {
            __bf16 ah = (__bf16)af[c]; ahi[c] = ah; alo[c] = (__bf16)(af[c] - (float)ah);
            __bf16 hh = (__bf16)hf[c]; hhi[c] = hh; hlo[c] = (__bf16)(hf[c] - (float)hh);
        }
        *(bf16x4*)&sIn[0][e][c4] = ahi;
        *(bf16x4*)&sIn[1][e][c4] = alo;
        *(bf16x4*)&sIn[2][e][c4] = hhi;
        *(bf16x4*)&sIn[3][e][c4] = hlo;
    }
    __syncthreads();

    const int lane = tid & 63, w = tid >> 6;     // w: 0..7
    const int r = lane & 15, quad = lane >> 4;
    const int jt = w;

    f32x4 acc[2][3][2];                  // [m][gate][mat]
#pragma unroll
    for (int m = 0; m < 2; m++)
#pragma unroll
        for (int g = 0; g < 3; g++)
#pragma unroll
            for (int mat = 0; mat < 2; mat++)
                acc[m][g][mat] = (f32x4){0.f, 0.f, 0.f, 0.f};

    bf16x8 B[2][12];
#pragma unroll
    for (int mat = 0; mat < 2; mat++)
#pragma unroll
    for (int g = 0; g < 3; g++)
#pragma unroll
    for (int sp = 0; sp < 2; sp++)
        B[0][mat * 6 + g * 2 + sp] = *(const bf16x8*)(Wg +
            ((((size_t)(mat * 2 + sp) * 4 + 0) * 24 + (g * 8 + jt)) * 64 + lane) * 8);

#pragma unroll
    for (int kc = 0; kc < 4; kc++) {
        const int cur = kc & 1, nxt = cur ^ 1;
        if (kc < 3) {
#pragma unroll
            for (int mat = 0; mat < 2; mat++)
#pragma unroll
            for (int g = 0; g < 3; g++)
#pragma unroll
            for (int sp = 0; sp < 2; sp++)
                B[nxt][mat * 6 + g * 2 + sp] = *(const bf16x8*)(Wg +
                    ((((size_t)(mat * 2 + sp) * 4 + (kc + 1)) * 24 + (g * 8 + jt)) * 64 + lane) * 8);
        }
        bf16x8 A[2][4];
#pragma unroll
        for (int m = 0; m < 2; m++)
#pragma unroll
            for (int s = 0; s < 4; s++)
                A[m][s] = *(const bf16x8*)&sIn[s][m * 16 + r][kc * 32 + quad * 8];
#pragma unroll
        for (int g = 0; g < 3; g++)
#pragma unroll
        for (int mat = 0; mat < 2; mat++) {
            bf16x8 bhi = B[cur][mat * 6 + g * 2 + 0];
            bf16x8 blo = B[cur][mat * 6 + g * 2 + 1];
            int s = mat * 2;
#pragma unroll
            for (int m = 0; m < 2; m++) {
                acc[m][g][mat] = __builtin_amdgcn_mfma_f32_16x16x32_bf16(
                    A[m][s], bhi, acc[m][g][mat], 0, 0, 0);
                acc[m][g][mat] = __builtin_amdgcn_mfma_f32_16x16x32_bf16(
                    A[m][s], blo, acc[m][g][mat], 0, 0, 0);
                acc[m][g][mat] = __builtin_amdgcn_mfma_f32_16x16x32_bf16(
                    A[m][s + 1], bhi, acc[m][g][mat], 0, 0, 0);
            }
        }
    }

    const int jcol = jt * 16 + r;
    float br_ = bih[jcol], bz_ = bih[128 + jcol], bn_ = bih[256 + jcol];
    float cr = bhh[jcol], cz = bhh[128 + jcol], cn = bhh[256 + jcol];
#pragma unroll
    for (int m = 0; m < 2; m++)
#pragma unroll
    for (int g4 = 0; g4 < 4; g4++) {
        int n = nb + m * 16 + quad * 4 + g4;
        if (n < n_nodes) {
            float ir = acc[m][0][0][g4], hr = acc[m][0][1][g4];
            float iz = acc[m][1][0][g4], hz = acc[m][1][1][g4];
            float in_ = acc[m][2][0][g4], hn = acc[m][2][1][g4];
            float hold = h[(size_t)n * H + jcol];
            float rr = 1.f / (1.f + expf(-(ir + br_ + hr + cr)));
            float zz = 1.f / (1.f + expf(-(iz + bz_ + hz + cz)));
            float nv = tanhf(in_ + bn_ + rr * (hn + cn));
            float out = (1.f - zz) * nv + zz * hold;
            h[(size_t)n * H + jcol] = out;
            hb[(size_t)n * H + jcol] = (__bf16)out;
        }
    }
}

// ---------------- readout: out = relu(h@Wr1+br1) @ Wr2 + br2 ---------------
__global__ __launch_bounds__(128) void k_readout(
    const float* __restrict__ h, const float* __restrict__ Wr1,
    const float* __restrict__ br1, const float* __restrict__ Wr2,
    const float* __restrict__ br2, float* __restrict__ out, int n_out)
{
    const int n0 = blockIdx.x * 16;
    const int tid = threadIdx.x;     // 128
    __shared__ float sh[16][H];      // 8 KB
    __shared__ float sRed[2][16];
    {
#pragma unroll
        for (int v = 0; v < 4; v++) {
            int idx = tid + 128 * v;          // float4 id, 512 total
            int e = idx >> 5, qq = (idx & 31) * 4;
            int n = n0 + e;
            if (n < n_out)
                *(float4*)&sh[e][qq] = *(const float4*)(h + (size_t)n * H + qq);
        }
    }
    __syncthreads();

    const int j = tid;
    float bb = br1[j];
    float acc[16];
#pragma unroll
    for (int e = 0; e < 16; e++) acc[e] = bb;
    for (int k = 0; k < H; k++) {
        float wv = Wr1[k * H + j];
#pragma unroll
        for (int e = 0; e < 16; e++) acc[e] += sh[e][k] * wv;
    }
    float w2 = Wr2[j];
    int lane = tid & 63, w = tid >> 6;
#pragma unroll
    for (int e = 0; e < 16; e++) {
        float val = fmaxf(acc[e], 0.f) * w2;
#pragma unroll
        for (int off = 32; off > 0; off >>= 1)
            val += __shfl_down(val, off, 64);
        if (lane == 0) sRed[w][e] = val;
    }
    __syncthreads();
    if (tid < 16 && n0 + tid < n_out)
        out[n0 + tid] = sRed[0][tid] + sRed[1][tid] + br2[0];
}

// ---------------------------------------------------------------------------
extern "C" void kernel_launch(void* const* d_in, const int* in_sizes, int n_in,
                              void* d_out, int out_size, void* d_ws, size_t ws_size,
                              hipStream_t stream)
{
    const float* x      = (const float*)d_in[0];
    const int*   eidx   = (const int*)d_in[1];
    const int*   etype  = (const int*)d_in[2];
    const float* Win    = (const float*)d_in[4];
    const float* bin    = (const float*)d_in[5];
    const float* W1     = (const float*)d_in[6];   // (3,2,256,128)
    const float* b1     = (const float*)d_in[7];   // (3,2,128)
    const float* W2     = (const float*)d_in[8];   // (3,2,128,128)
    const float* b2     = (const float*)d_in[9];   // (3,2,128)
    const float* Wih    = (const float*)d_in[10];  // (3,128,384)
    const float* bih    = (const float*)d_in[11];  // (3,384)
    const float* Whh    = (const float*)d_in[12];  // (3,128,384)
    const float* bhh    = (const float*)d_in[13];  // (3,384)
    const float* Wr1    = (const float*)d_in[14];
    const float* br1    = (const float*)d_in[15];
    const float* Wr2    = (const float*)d_in[16];
    const float* br2    = (const float*)d_in[17];

    const int n_nodes = in_sizes[0] / FEAT;
    const int n_edges = in_sizes[1] / 2;
    const int L = 3;
    const size_t nh = (size_t)n_nodes * H;

    const int* src = eidx;
    const int* dst = eidx + n_edges;

    // workspace carve-up
    float*  h    = (float*)d_ws;                    // 25.6 MB
    float*  agg  = h + nh;                          // 25.6 MB
    __bf16* hb   = (__bf16*)(agg + nh);             // 12.8 MB
    __bf16* Wsw  = hb + nh;                         // 6*12*4096 bf16
    __bf16* Wg   = Wsw + 6 * 12 * 4096;             // 3*WG_PER_LAYER bf16
    int* bucket  = (int*)(Wg + 3 * WG_PER_LAYER);   // n_edges
    int* cnt     = bucket + n_edges;                // 2*nn (also k_place cursors)
    int* offs    = cnt + 2 * n_nodes;               // 2*nn + 1
    int* bsum    = offs + 2 * n_nodes + 1;          // scan block sums

    const int nscan = 2 * n_nodes;
    const int nb = (nscan + 1023) / 1024;

    hipMemsetAsync(cnt, 0, (size_t)nscan * sizeof(int), stream);

    k_wconv<<<(6 * 12 * 4096 + 255) / 256, 256, 0, stream>>>(W1, W2, Wsw);
    k_wgconv<<<(3 * WG_PER_LAYER + 255) / 256, 256, 0, stream>>>(Wih, Whh, Wg);
    k_input<<<((int)nh + 255) / 256, 256, 0, stream>>>(x, Win, bin, h, hb, n_nodes);

    const int eb = (n_edges + 255) / 256;
    k_hist <<<eb, 256, 0, stream>>>(etype, dst, cnt, n_edges, n_nodes);
    k_scan1<<<nb, 1024, 0, stream>>>(cnt, bsum, nscan);
    k_scan2<<<1, 128, 0, stream>>>(bsum, offs, nb, nscan);
    k_scan3<<<nb, 1024, 0, stream>>>(cnt, bsum, offs, nscan);
    k_place<<<eb, 256, 0, stream>>>(etype, dst, offs, cnt, bucket, n_edges, n_nodes);

    // agg zeroed once here; k_gru re-zeroes it for the following layer
    hipMemsetAsync(agg, 0, nh * sizeof(float), stream);

    const dim3 mgrid((n_edges + TE2 - 1) / TE2, 2);
    for (int l = 0; l < L; l++) {
        k_msg<<<mgrid, 512, 0, stream>>>(
            hb, bucket, offs, src, dst,
            Wsw + (size_t)l * 2 * 12 * 4096,
            b1 + (size_t)l * 2 * H, b2 + (size_t)l * 2 * H,
            agg, n_edges, n_nodes);
        k_gru<<<(n_nodes + 31) / 32, 512, 0, stream>>>(
            h, hb, agg,
            Wg + (size_t)l * WG_PER_LAYER,
            bih + (size_t)l * 384, bhh + (size_t)l * 384,
            n_nodes);
    }

    k_readout<<<(out_size + 15) / 16, 128, 0, stream>>>(
        h, Wr1, br1, Wr2, br2, (float*)d_out, out_size);
}

// Round 13
// 573.601 us; speedup vs baseline: 1.2182x; 1.2182x over previous
//
#include <hip/hip_runtime.h>
#include <math.h>

// ---------------------------------------------------------------------------
// TannerGNN. Round 13: revert k_msg to the exact R9 kernel (89us measured;
// R10/R11/R12 all regressed it — limited occupancy protects L2 locality of
// hb gathers + agg atomics). New: k_readout converted to split-precision
// MFMA (same verified pattern as k_gru) — ~30us -> ~8us.
// N_NODES=50000, N_EDGES=400000, H=128, L=3, T=2, FEAT=4, N_DATA=40000.
// ---------------------------------------------------------------------------

#define H 128
#define TE2 128        // edges per message block
#define MS2 132        // sMsg row stride in f32
#define HS  136        // sHid/sIn row stride in bf16
#define FEAT 4
#define WG_PER_LAYER 196608   // 2 mat * 2 split * 4 kc * 24 jtg * 64 lane * 8
#define WR_TOTAL 32768        // 2 split * 4 kc * 8 jtg * 64 lane * 8

typedef __bf16 bf16x8 __attribute__((ext_vector_type(8)));
typedef __bf16 bf16x4 __attribute__((ext_vector_type(4)));
typedef float  f32x4  __attribute__((ext_vector_type(4)));

// ---------------- input projection: h = relu(x @ W_in + b_in) --------------
__global__ __launch_bounds__(256) void k_input(
    const float* __restrict__ x, const float* __restrict__ Win,
    const float* __restrict__ bin, float* __restrict__ h,
    __bf16* __restrict__ hb, int n_nodes)
{
    int idx = blockIdx.x * 256 + threadIdx.x;
    if (idx >= n_nodes * H) return;
    int n = idx >> 7, j = idx & 127;
    float acc = bin[j];
#pragma unroll
    for (int f = 0; f < FEAT; f++)
        acc += x[n * FEAT + f] * Win[f * H + j];
    float v = fmaxf(acc, 0.f);
    h[idx] = v;
    hb[idx] = (__bf16)v;
}

// ---------------- message-weight conversion: bf16, MFMA-fragment order -----
__global__ __launch_bounds__(256) void k_wconv(
    const float* __restrict__ W1, const float* __restrict__ W2,
    __bf16* __restrict__ Wsw)
{
    int gid = blockIdx.x * 256 + threadIdx.x;
    const int per_lt = 12 * 4096;
    if (gid >= 6 * per_lt) return;
    int lt = gid / per_lt, rem = gid % per_lt;
    int chunk = rem >> 12;
    int within = rem & 4095;
    int ct = within >> 9;
    int lane = (within >> 3) & 63;
    int j = within & 7;
    int r = lane & 15, quad = lane >> 4;
    int n = ct * 16 + r;
    float v;
    if (chunk < 8) {
        int k = chunk * 32 + quad * 8 + j;
        v = W1[((size_t)lt * 256 + k) * 128 + n];
    } else {
        int k = (chunk - 8) * 32 + quad * 8 + j;
        v = W2[((size_t)lt * 128 + k) * 128 + n];
    }
    Wsw[gid] = (__bf16)v;
}

// ---------------- GRU-weight conversion: hi/lo split, B-fragment order -----
__global__ __launch_bounds__(256) void k_wgconv(
    const float* __restrict__ Wih, const float* __restrict__ Whh,
    __bf16* __restrict__ Wg)
{
    int gid = blockIdx.x * 256 + threadIdx.x;
    if (gid >= 3 * WG_PER_LAYER) return;
    int layer = gid / WG_PER_LAYER, rem = gid % WG_PER_LAYER;
    int t = rem & 7;
    int lane = (rem >> 3) & 63;
    int jtg = (rem >> 9) % 24;
    int mk = rem / 12288;          // (mat*2+split)*4 + kc, 0..15
    int kc = mk & 3;
    int msplit = mk >> 2;          // 0..3
    int mat = msplit >> 1, split = msplit & 1;
    int r = lane & 15, quad = lane >> 4;
    int k = kc * 32 + quad * 8 + t;
    int n = jtg * 16 + r;
    const float* W = (mat ? Whh : Wih) + (size_t)layer * 128 * 384;
    float v = W[(size_t)k * 384 + n];
    __bf16 hi = (__bf16)v;
    Wg[gid] = split ? (__bf16)(v - (float)hi) : hi;
}

// ---------------- readout-weight conversion: hi/lo split -------------------
// Wr1s[((split*4 + kc)*8 + jtg)*512 + lane*8 + t], k = kc*32+(lane>>4)*8+t,
// n = jtg*16 + (lane&15); value = Wr1[k*128+n].
__global__ __launch_bounds__(256) void k_wrconv(
    const float* __restrict__ Wr1, __bf16* __restrict__ Wr1s)
{
    int gid = blockIdx.x * 256 + threadIdx.x;
    if (gid >= WR_TOTAL) return;
    int t = gid & 7;
    int lane = (gid >> 3) & 63;
    int jtg = (gid >> 9) & 7;
    int kc = (gid >> 12) & 3;
    int split = gid >> 14;
    int r = lane & 15, quad = lane >> 4;
    int k = kc * 32 + quad * 8 + t;
    int n = jtg * 16 + r;
    float v = Wr1[(size_t)k * H + n];
    __bf16 hi = (__bf16)v;
    Wr1s[gid] = split ? (__bf16)(v - (float)hi) : hi;
}

// ---------------- counting sort by key = type*nn + dst ---------------------
__global__ __launch_bounds__(256) void k_hist(
    const int* __restrict__ et, const int* __restrict__ dst,
    int* __restrict__ cnt, int n_edges, int nn)
{
    int i = blockIdx.x * 256 + threadIdx.x;
    if (i < n_edges) atomicAdd(&cnt[et[i] * nn + dst[i]], 1);
}

__global__ __launch_bounds__(1024) void k_scan1(
    const int* __restrict__ cnt, int* __restrict__ bsum, int n)
{
    int i = blockIdx.x * 1024 + threadIdx.x;
    int v = (i < n) ? cnt[i] : 0;
#pragma unroll
    for (int off = 32; off > 0; off >>= 1) v += __shfl_down(v, off, 64);
    __shared__ int ws[16];
    int lane = threadIdx.x & 63, w = threadIdx.x >> 6;
    if (lane == 0) ws[w] = v;
    __syncthreads();
    if (threadIdx.x < 16) {
        int x = ws[threadIdx.x];
#pragma unroll
        for (int off = 8; off > 0; off >>= 1) x += __shfl_down(x, off, 64);
        if (threadIdx.x == 0) bsum[blockIdx.x] = x;
    }
}

__global__ __launch_bounds__(128) void k_scan2(
    int* __restrict__ bsum, int* __restrict__ offs, int nb, int n)
{
    int lane = threadIdx.x & 63, w = threadIdx.x >> 6;
    int v = (threadIdx.x < nb) ? bsum[threadIdx.x] : 0;
    int orig = v;
#pragma unroll
    for (int off = 1; off < 64; off <<= 1) {
        int t = __shfl_up(v, off, 64);
        if (lane >= off) v += t;
    }
    __shared__ int w0sum;
    if (threadIdx.x == 63) w0sum = v;
    __syncthreads();
    int ex = v - orig + (w ? w0sum : 0);
    if (threadIdx.x < nb) bsum[threadIdx.x] = ex;
    if (threadIdx.x == nb - 1) offs[n] = ex + orig;
}

__global__ __launch_bounds__(1024) void k_scan3(
    const int* __restrict__ cnt, const int* __restrict__ bsum,
    int* __restrict__ offs, int n)
{
    int i = blockIdx.x * 1024 + threadIdx.x;
    int v = (i < n) ? cnt[i] : 0;
    int orig = v;
    int lane = threadIdx.x & 63, w = threadIdx.x >> 6;
#pragma unroll
    for (int off = 1; off < 64; off <<= 1) {
        int t = __shfl_up(v, off, 64);
        if (lane >= off) v += t;
    }
    __shared__ int ws[16];
    if (lane == 63) ws[w] = v;
    __syncthreads();
    if (threadIdx.x < 16) {
        int x = ws[threadIdx.x];
#pragma unroll
        for (int off = 1; off < 16; off <<= 1) {
            int t = __shfl_up(x, off, 64);
            if (lane >= off) x += t;
        }
        ws[threadIdx.x] = x;
    }
    __syncthreads();
    int wbase = w ? ws[w - 1] : 0;
    if (i < n) offs[i] = bsum[blockIdx.x] + wbase + v - orig;
}

__global__ __launch_bounds__(256) void k_place(
    const int* __restrict__ et, const int* __restrict__ dst,
    const int* __restrict__ offs, int* __restrict__ cnt,
    int* __restrict__ bucket, int n_edges, int nn)
{
    int i = blockIdx.x * 256 + threadIdx.x;
    if (i < n_edges) {
        int key = et[i] * nn + dst[i];
        int p = atomicAdd(&cnt[key], -1) - 1;
        bucket[offs[key] + p] = i;
    }
}

// ---------------- fused MFMA message kernel (exact R9, 89us measured) ------
__global__ __launch_bounds__(512, 4) void k_msg(
    const __bf16* __restrict__ hb,
    const int* __restrict__ bucket, const int* __restrict__ offs,
    const int* __restrict__ src, const int* __restrict__ dst,
    const __bf16* __restrict__ Wsw, const float* __restrict__ b1l,
    const float* __restrict__ b2l,
    float* __restrict__ agg, int n_edges, int nn)
{
    const int t = blockIdx.y;
    const int c0 = offs[nn];
    const int cnt = t ? (n_edges - c0) : c0;
    const int base = t ? c0 : 0;
    const int start = blockIdx.x * TE2;
    if (start >= cnt) return;

    const __bf16* __restrict__ W = Wsw + (size_t)t * 12 * 4096;
    const float*  __restrict__ b1 = b1l + t * H;
    const float*  __restrict__ b2 = b2l + t * H;

    __shared__ __bf16 sW[4096];            // 8 KB weight chunk
    __shared__ float  sMsg[TE2 * MS2];     // 67584 B; sHid aliases per-wave
    __shared__ int    sDstV[TE2];

    const int tid  = threadIdx.x;
    const int lane = tid & 63;
    const int w    = tid >> 6;
    const int r    = lane & 15;
    const int quad = lane >> 4;

    f32x4 wreg[12];
#pragma unroll
    for (int c = 0; c < 12; c++)
        wreg[c] = *(const f32x4*)(W + c * 4096 + tid * 8);

    if (tid < TE2) {
        int i = start + tid;
        sDstV[tid] = (i < cnt) ? dst[bucket[base + i]] : -1;
    }

    int ei = start + w * 16 + r;
    int e = bucket[base + (ei < cnt ? ei : cnt - 1)];
    const __bf16* aps = hb + (size_t)src[e] * H;
    const __bf16* apd = hb + (size_t)dst[e] * H;

    bf16x8 afS[4];
#pragma unroll
    for (int i = 0; i < 4; i++)
        afS[i] = *(const bf16x8*)(aps + i * 32 + quad * 8);

    __syncthreads();

    // ---- Phase A: hidT = (cat @ W1)^T, K=256 in 8 chunks ----
    f32x4 acc[8];
#pragma unroll
    for (int ct = 0; ct < 8; ct++) acc[ct] = (f32x4){0.f, 0.f, 0.f, 0.f};

    bf16x8 afD[4];
#pragma unroll
    for (int kc = 0; kc < 8; kc++) {
        __syncthreads();
        *(f32x4*)(sW + tid * 8) = wreg[kc];
        __syncthreads();
        if (kc == 2) {
#pragma unroll
            for (int i = 0; i < 4; i++)
                afD[i] = *(const bf16x8*)(apd + i * 32 + quad * 8);
        }
        bf16x8 b = (kc < 4) ? afS[kc] : afD[kc - 4];
#pragma unroll
        for (int ct = 0; ct < 8; ct++) {
            bf16x8 a = *(const bf16x8*)(sW + ct * 512 + lane * 8);
            acc[ct] = __builtin_amdgcn_mfma_f32_16x16x32_bf16(a, b, acc[ct], 0, 0, 0);
        }
    }

    // epilogue A: bias + relu -> bf16 -> sHid[edge=r][feat] (own-wave strip)
    __bf16* sHid = (__bf16*)(sMsg + w * 16 * MS2);   // 16 rows x HS stride
#pragma unroll
    for (int ct = 0; ct < 8; ct++) {
        f32x4 bb4 = *(const f32x4*)(b1 + ct * 16 + quad * 4);
        bf16x4 hv;
#pragma unroll
        for (int g = 0; g < 4; g++)
            hv[g] = (__bf16)fmaxf(acc[ct][g] + bb4[g], 0.f);
        *(bf16x4*)(sHid + r * HS + ct * 16 + quad * 4) = hv;
    }

    // ---- Phase B: msgT = (hid @ W2)^T, K=128 in 4 chunks ----
    f32x4 acc2[8];
#pragma unroll
    for (int ct = 0; ct < 8; ct++) acc2[ct] = (f32x4){0.f, 0.f, 0.f, 0.f};
#pragma unroll
    for (int kc = 0; kc < 4; kc++) {
        __syncthreads();
        *(f32x4*)(sW + tid * 8) = wreg[8 + kc];
        __syncthreads();
        bf16x8 b = *(const bf16x8*)(sHid + r * HS + kc * 32 + quad * 8);
#pragma unroll
        for (int ct = 0; ct < 8; ct++) {
            bf16x8 a = *(const bf16x8*)(sW + ct * 512 + lane * 8);
            acc2[ct] = __builtin_amdgcn_mfma_f32_16x16x32_bf16(a, b, acc2[ct], 0, 0, 0);
        }
    }

    // ---- Phase C: msgs (+bias) -> sMsg[edge = 16w+r][feat], vectorized ----
#pragma unroll
    for (int ct = 0; ct < 8; ct++) {
        f32x4 bb4 = *(const f32x4*)(b2 + ct * 16 + quad * 4);
        f32x4 mv;
#pragma unroll
        for (int g = 0; g < 4; g++)
            mv[g] = acc2[ct][g] + bb4[g];
        *(f32x4*)(sMsg + (w * 16 + r) * MS2 + ct * 16 + quad * 4) = mv;
    }
    __syncthreads();

    // segmented reduction over dst-sorted rows; one atomic per run per col
    {
        int j = tid & 127, strip = tid >> 7;
        int e0 = strip * 32;
        float run = 0.f; int curd = -1;
        for (int q = 0; q < 32; q++) {
            int d = sDstV[e0 + q];
            float v = sMsg[(e0 + q) * MS2 + j];
            if (d != curd) {
                if (curd >= 0) atomicAdd(agg + (size_t)curd * H + j, run);
                run = 0.f; curd = d;
            }
            if (d >= 0) run += v;
        }
        if (curd >= 0) atomicAdd(agg + (size_t)curd * H + j, run);
    }
}

// ---------------- GRU cell: split-precision MFMA, double-buffered B --------
// Also zeroes agg (for the next layer) after reading it.
__global__ __launch_bounds__(512, 2) void k_gru(
    float* __restrict__ h, __bf16* __restrict__ hb,
    float* __restrict__ agg,
    const __bf16* __restrict__ Wg,
    const float* __restrict__ bih, const float* __restrict__ bhh,
    int n_nodes)
{
    const int nb = blockIdx.x * 32;
    const int tid = threadIdx.x;
    __shared__ __bf16 sIn[4][32][HS];   // agg_hi, agg_lo, h_hi, h_lo (34.8 KB)

#pragma unroll
    for (int v = 0; v < 2; v++) {
        int idx = tid + 512 * v;
        int e = idx >> 5, c4 = (idx & 31) * 4;
        int n = nb + e;
        float4 av = {0.f, 0.f, 0.f, 0.f}, hv = {0.f, 0.f, 0.f, 0.f};
        if (n < n_nodes) {
            av = *(const float4*)(agg + (size_t)n * H + c4);
            hv = *(const float4*)(h + (size_t)n * H + c4);
            float4 z = {0.f, 0.f, 0.f, 0.f};
            *(float4*)(agg + (size_t)n * H + c4) = z;   // ready for next layer
        }
        bf16x4 ahi, alo, hhi, hlo;
        float af[4] = {av.x, av.y, av.z, av.w};
        float hf[4] = {hv.x, hv.y, hv.z, hv.w};
#pragma unroll
        for (int c = 0; c < 4; c++) {
            __bf16 ah = (__bf16)af[c]; ahi[c] = ah; alo[c] = (__bf16)(af[c] - (float)ah);
            __bf16 hh = (__bf16)hf[c]; hhi[c] = hh; hlo[c] = (__bf16)(hf[c] - (float)hh);
        }
        *(bf16x4*)&sIn[0][e][c4] = ahi;
        *(bf16x4*)&sIn[1][e][c4] = alo;
        *(bf16x4*)&sIn[2][e][c4] = hhi;
        *(bf16x4*)&sIn[3][e][c4] = hlo;
    }
    __syncthreads();

    const int lane = tid & 63, w = tid >> 6;     // w: 0..7
    const int r = lane & 15, quad = lane >> 4;
    const int jt = w;

    f32x4 acc[2][3][2];                  // [m][gate][mat]
#pragma unroll
    for (int m = 0; m < 2; m++)
#pragma unroll
        for (int g = 0; g < 3; g++)
#pragma unroll
            for (int mat = 0; mat < 2; mat++)
                acc[m][g][mat] = (f32x4){0.f, 0.f, 0.f, 0.f};

    bf16x8 B[2][12];
#pragma unroll
    for (int mat = 0; mat < 2; mat++)
#pragma unroll
    for (int g = 0; g < 3; g++)
#pragma unroll
    for (int sp = 0; sp < 2; sp++)
        B[0][mat * 6 + g * 2 + sp] = *(const bf16x8*)(Wg +
            ((((size_t)(mat * 2 + sp) * 4 + 0) * 24 + (g * 8 + jt)) * 64 + lane) * 8);

#pragma unroll
    for (int kc = 0; kc < 4; kc++) {
        const int cur = kc & 1, nxt = cur ^ 1;
        if (kc < 3) {
#pragma unroll
            for (int mat = 0; mat < 2; mat++)
#pragma unroll
            for (int g = 0; g < 3; g++)
#pragma unroll
            for (int sp = 0; sp < 2; sp++)
                B[nxt][mat * 6 + g * 2 + sp] = *(const bf16x8*)(Wg +
                    ((((size_t)(mat * 2 + sp) * 4 + (kc + 1)) * 24 + (g * 8 + jt)) * 64 + lane) * 8);
        }
        bf16x8 A[2][4];
#pragma unroll
        for (int m = 0; m < 2; m++)
#pragma unroll
            for (int s = 0; s < 4; s++)
                A[m][s] = *(const bf16x8*)&sIn[s][m * 16 + r][kc * 32 + quad * 8];
#pragma unroll
        for (int g = 0; g < 3; g++)
#pragma unroll
        for (int mat = 0; mat < 2; mat++) {
            bf16x8 bhi = B[cur][mat * 6 + g * 2 + 0];
            bf16x8 blo = B[cur][mat * 6 + g * 2 + 1];
            int s = mat * 2;
#pragma unroll
            for (int m = 0; m < 2; m++) {
                acc[m][g][mat] = __builtin_amdgcn_mfma_f32_16x16x32_bf16(
                    A[m][s], bhi, acc[m][g][mat], 0, 0, 0);
                acc[m][g][mat] = __builtin_amdgcn_mfma_f32_16x16x32_bf16(
                    A[m][s], blo, acc[m][g][mat], 0, 0, 0);
                acc[m][g][mat] = __builtin_amdgcn_mfma_f32_16x16x32_bf16(
                    A[m][s + 1], bhi, acc[m][g][mat], 0, 0, 0);
            }
        }
    }

    const int jcol = jt * 16 + r;
    float br_ = bih[jcol], bz_ = bih[128 + jcol], bn_ = bih[256 + jcol];
    float cr = bhh[jcol], cz = bhh[128 + jcol], cn = bhh[256 + jcol];
#pragma unroll
    for (int m = 0; m < 2; m++)
#pragma unroll
    for (int g4 = 0; g4 < 4; g4++) {
        int n = nb + m * 16 + quad * 4 + g4;
        if (n < n_nodes) {
            float ir = acc[m][0][0][g4], hr = acc[m][0][1][g4];
            float iz = acc[m][1][0][g4], hz = acc[m][1][1][g4];
            float in_ = acc[m][2][0][g4], hn = acc[m][2][1][g4];
            float hold = h[(size_t)n * H + jcol];
            float rr = 1.f / (1.f + expf(-(ir + br_ + hr + cr)));
            float zz = 1.f / (1.f + expf(-(iz + bz_ + hz + cz)));
            float nv = tanhf(in_ + bn_ + rr * (hn + cn));
            float out = (1.f - zz) * nv + zz * hold;
            h[(size_t)n * H + jcol] = out;
            hb[(size_t)n * H + jcol] = (__bf16)out;
        }
    }
}

// ---------------- readout: split-precision MFMA ----------------------------
// 32 nodes/block, 256 thr (4 waves). G = h @ Wr1 via hi/lo 3-term MFMA
// (k_gru's verified fragment pattern); out = sum_j relu(G+br1)*Wr2 + br2.
// Wave w owns j-tiles {2w, 2w+1}; shfl-xor reduce over r, LDS over waves.
__global__ __launch_bounds__(256, 4) void k_readout(
    const float* __restrict__ h, const __bf16* __restrict__ Wr1s,
    const float* __restrict__ br1, const float* __restrict__ Wr2,
    const float* __restrict__ br2, float* __restrict__ out, int n_out)
{
    const int nb = blockIdx.x * 32;
    const int tid = threadIdx.x;
    __shared__ __bf16 sIn[2][32][HS];   // h hi/lo (17.4 KB)
    __shared__ float sRed[4][32];

#pragma unroll
    for (int v = 0; v < 4; v++) {
        int idx = tid + 256 * v;            // float4 id, 1024 total
        int e = idx >> 5, c4 = (idx & 31) * 4;
        int n = nb + e;
        float4 hv = {0.f, 0.f, 0.f, 0.f};
        if (n < n_out)
            hv = *(const float4*)(h + (size_t)n * H + c4);
        float hf[4] = {hv.x, hv.y, hv.z, hv.w};
        bf16x4 hhi, hlo;
#pragma unroll
        for (int c = 0; c < 4; c++) {
            __bf16 hh = (__bf16)hf[c];
            hhi[c] = hh; hlo[c] = (__bf16)(hf[c] - (float)hh);
        }
        *(bf16x4*)&sIn[0][e][c4] = hhi;
        *(bf16x4*)&sIn[1][e][c4] = hlo;
    }
    __syncthreads();

    const int lane = tid & 63, w = tid >> 6;
    const int r = lane & 15, quad = lane >> 4;

    f32x4 acc[2][2];                 // [m][j]
#pragma unroll
    for (int m = 0; m < 2; m++)
#pragma unroll
        for (int j = 0; j < 2; j++)
            acc[m][j] = (f32x4){0.f, 0.f, 0.f, 0.f};

#pragma unroll
    for (int kc = 0; kc < 4; kc++) {
        bf16x8 A[2][2];
#pragma unroll
        for (int m = 0; m < 2; m++)
#pragma unroll
            for (int s = 0; s < 2; s++)
                A[m][s] = *(const bf16x8*)&sIn[s][m * 16 + r][kc * 32 + quad * 8];
#pragma unroll
        for (int j = 0; j < 2; j++) {
            int jtg = w * 2 + j;
            bf16x8 bhi = *(const bf16x8*)(Wr1s +
                ((size_t)(0 * 4 + kc) * 8 + jtg) * 512 + lane * 8);
            bf16x8 blo = *(const bf16x8*)(Wr1s +
                ((size_t)(1 * 4 + kc) * 8 + jtg) * 512 + lane * 8);
#pragma unroll
            for (int m = 0; m < 2; m++) {
                acc[m][j] = __builtin_amdgcn_mfma_f32_16x16x32_bf16(
                    A[m][0], bhi, acc[m][j], 0, 0, 0);
                acc[m][j] = __builtin_amdgcn_mfma_f32_16x16x32_bf16(
                    A[m][0], blo, acc[m][j], 0, 0, 0);
                acc[m][j] = __builtin_amdgcn_mfma_f32_16x16x32_bf16(
                    A[m][1], bhi, acc[m][j], 0, 0, 0);
            }
        }
    }

    // epilogue: relu(G + br1)*Wr2, reduce over cols
    float part[2][4];
#pragma unroll
    for (int m = 0; m < 2; m++)
#pragma unroll
        for (int g = 0; g < 4; g++) part[m][g] = 0.f;
#pragma unroll
    for (int j = 0; j < 2; j++) {
        int col = (w * 2 + j) * 16 + r;
        float b1v = br1[col], w2v = Wr2[col];
#pragma unroll
        for (int m = 0; m < 2; m++)
#pragma unroll
            for (int g = 0; g < 4; g++)
                part[m][g] += fmaxf(acc[m][j][g] + b1v, 0.f) * w2v;
    }
#pragma unroll
    for (int mask = 1; mask < 16; mask <<= 1)
#pragma unroll
        for (int m = 0; m < 2; m++)
#pragma unroll
            for (int g = 0; g < 4; g++)
                part[m][g] += __shfl_xor(part[m][g], mask, 16);
    if (r == 0) {
#pragma unroll
        for (int m = 0; m < 2; m++)
#pragma unroll
            for (int g = 0; g < 4; g++)
                sRed[w][m * 16 + quad * 4 + g] = part[m][g];
    }
    __syncthreads();
    if (tid < 32) {
        int n = nb + tid;
        if (n < n_out)
            out[n] = sRed[0][tid] + sRed[1][tid] + sRed[2][tid] + sRed[3][tid]
                     + br2[0];
    }
}

// ---------------------------------------------------------------------------
extern "C" void kernel_launch(void* const* d_in, const int* in_sizes, int n_in,
                              void* d_out, int out_size, void* d_ws, size_t ws_size,
                              hipStream_t stream)
{
    const float* x      = (const float*)d_in[0];
    const int*   eidx   = (const int*)d_in[1];
    const int*   etype  = (const int*)d_in[2];
    const float* Win    = (const float*)d_in[4];
    const float* bin    = (const float*)d_in[5];
    const float* W1     = (const float*)d_in[6];   // (3,2,256,128)
    const float* b1     = (const float*)d_in[7];   // (3,2,128)
    const float* W2     = (const float*)d_in[8];   // (3,2,128,128)
    const float* b2     = (const float*)d_in[9];   // (3,2,128)
    const float* Wih    = (const float*)d_in[10];  // (3,128,384)
    const float* bih    = (const float*)d_in[11];  // (3,384)
    const float* Whh    = (const float*)d_in[12];  // (3,128,384)
    const float* bhh    = (const float*)d_in[13];  // (3,384)
    const float* Wr1    = (const float*)d_in[14];
    const float* br1    = (const float*)d_in[15];
    const float* Wr2    = (const float*)d_in[16];
    const float* br2    = (const float*)d_in[17];

    const int n_nodes = in_sizes[0] / FEAT;
    const int n_edges = in_sizes[1] / 2;
    const int L = 3;
    const size_t nh = (size_t)n_nodes * H;

    const int* src = eidx;
    const int* dst = eidx + n_edges;

    // workspace carve-up
    float*  h    = (float*)d_ws;                    // 25.6 MB
    float*  agg  = h + nh;                          // 25.6 MB
    __bf16* hb   = (__bf16*)(agg + nh);             // 12.8 MB
    __bf16* Wsw  = hb + nh;                         // 6*12*4096 bf16
    __bf16* Wg   = Wsw + 6 * 12 * 4096;             // 3*WG_PER_LAYER bf16
    __bf16* Wr1s = Wg + 3 * WG_PER_LAYER;           // WR_TOTAL bf16
    int* bucket  = (int*)(Wr1s + WR_TOTAL);         // n_edges
    int* cnt     = bucket + n_edges;                // 2*nn (also k_place cursors)
    int* offs    = cnt + 2 * n_nodes;               // 2*nn + 1
    int* bsum    = offs + 2 * n_nodes + 1;          // scan block sums

    const int nscan = 2 * n_nodes;
    const int nb = (nscan + 1023) / 1024;

    hipMemsetAsync(cnt, 0, (size_t)nscan * sizeof(int), stream);

    k_wconv<<<(6 * 12 * 4096 + 255) / 256, 256, 0, stream>>>(W1, W2, Wsw);
    k_wgconv<<<(3 * WG_PER_LAYER + 255) / 256, 256, 0, stream>>>(Wih, Whh, Wg);
    k_wrconv<<<(WR_TOTAL + 255) / 256, 256, 0, stream>>>(Wr1, Wr1s);
    k_input<<<((int)nh + 255) / 256, 256, 0, stream>>>(x, Win, bin, h, hb, n_nodes);

    const int eb = (n_edges + 255) / 256;
    k_hist <<<eb, 256, 0, stream>>>(etype, dst, cnt, n_edges, n_nodes);
    k_scan1<<<nb, 1024, 0, stream>>>(cnt, bsum, nscan);
    k_scan2<<<1, 128, 0, stream>>>(bsum, offs, nb, nscan);
    k_scan3<<<nb, 1024, 0, stream>>>(cnt, bsum, offs, nscan);
    k_place<<<eb, 256, 0, stream>>>(etype, dst, offs, cnt, bucket, n_edges, n_nodes);

    // agg zeroed once here; k_gru re-zeroes it for the following layer
    hipMemsetAsync(agg, 0, nh * sizeof(float), stream);

    const dim3 mgrid((n_edges + TE2 - 1) / TE2, 2);
    for (int l = 0; l < L; l++) {
        k_msg<<<mgrid, 512, 0, stream>>>(
            hb, bucket, offs, src, dst,
            Wsw + (size_t)l * 2 * 12 * 4096,
            b1 + (size_t)l * 2 * H, b2 + (size_t)l * 2 * H,
            agg, n_edges, n_nodes);
        k_gru<<<(n_nodes + 31) / 32, 512, 0, stream>>>(
            h, hb, agg,
            Wg + (size_t)l * WG_PER_LAYER,
            bih + (size_t)l * 384, bhh + (size_t)l * 384,
            n_nodes);
    }

    k_readout<<<(out_size + 31) / 32, 256, 0, stream>>>(
        h, Wr1s, br1, Wr2, br2, (float*)d_out, out_size);
}

// Round 14
// 568.965 us; speedup vs baseline: 1.2282x; 1.0081x over previous
//
#include <hip/hip_runtime.h>
#include <math.h>

// ---------------------------------------------------------------------------
// TannerGNN. Round 14: k_gru wave-specialized by matrix (16 waves/block of
// 1024 thr; wave w: mat=w>>3, jt=w&7) to halve per-wave VGPR (B[2][6]+acc24
// => ~115 <= 128) and double resident waves 8->16/CU. Gate epilogue joins
// the two matrices via an LDS exchange (aliases dead sIn, stride 132).
// Bit-identical accumulation => absmax must stay exactly 0.02734375.
// k_msg = exact R9 (89us); readout = R13 MFMA version. Everything else R13.
// N_NODES=50000, N_EDGES=400000, H=128, L=3, T=2, FEAT=4, N_DATA=40000.
// ---------------------------------------------------------------------------

#define H 128
#define TE2 128        // edges per message block
#define MS2 132        // sMsg row stride in f32
#define HS  136        // sHid/sIn row stride in bf16
#define EXS 132        // sEx row stride in f32 (2-way banks)
#define FEAT 4
#define WG_PER_LAYER 196608   // 2 mat * 2 split * 4 kc * 24 jtg * 64 lane * 8
#define WR_TOTAL 32768        // 2 split * 4 kc * 8 jtg * 64 lane * 8

typedef __bf16 bf16x8 __attribute__((ext_vector_type(8)));
typedef __bf16 bf16x4 __attribute__((ext_vector_type(4)));
typedef float  f32x4  __attribute__((ext_vector_type(4)));

// ---------------- input projection: h = relu(x @ W_in + b_in) --------------
__global__ __launch_bounds__(256) void k_input(
    const float* __restrict__ x, const float* __restrict__ Win,
    const float* __restrict__ bin, float* __restrict__ h,
    __bf16* __restrict__ hb, int n_nodes)
{
    int idx = blockIdx.x * 256 + threadIdx.x;
    if (idx >= n_nodes * H) return;
    int n = idx >> 7, j = idx & 127;
    float acc = bin[j];
#pragma unroll
    for (int f = 0; f < FEAT; f++)
        acc += x[n * FEAT + f] * Win[f * H + j];
    float v = fmaxf(acc, 0.f);
    h[idx] = v;
    hb[idx] = (__bf16)v;
}

// ---------------- message-weight conversion: bf16, MFMA-fragment order -----
__global__ __launch_bounds__(256) void k_wconv(
    const float* __restrict__ W1, const float* __restrict__ W2,
    __bf16* __restrict__ Wsw)
{
    int gid = blockIdx.x * 256 + threadIdx.x;
    const int per_lt = 12 * 4096;
    if (gid >= 6 * per_lt) return;
    int lt = gid / per_lt, rem = gid % per_lt;
    int chunk = rem >> 12;
    int within = rem & 4095;
    int ct = within >> 9;
    int lane = (within >> 3) & 63;
    int j = within & 7;
    int r = lane & 15, quad = lane >> 4;
    int n = ct * 16 + r;
    float v;
    if (chunk < 8) {
        int k = chunk * 32 + quad * 8 + j;
        v = W1[((size_t)lt * 256 + k) * 128 + n];
    } else {
        int k = (chunk - 8) * 32 + quad * 8 + j;
        v = W2[((size_t)lt * 128 + k) * 128 + n];
    }
    Wsw[gid] = (__bf16)v;
}

// ---------------- GRU-weight conversion: hi/lo split, B-fragment order -----
__global__ __launch_bounds__(256) void k_wgconv(
    const float* __restrict__ Wih, const float* __restrict__ Whh,
    __bf16* __restrict__ Wg)
{
    int gid = blockIdx.x * 256 + threadIdx.x;
    if (gid >= 3 * WG_PER_LAYER) return;
    int layer = gid / WG_PER_LAYER, rem = gid % WG_PER_LAYER;
    int t = rem & 7;
    int lane = (rem >> 3) & 63;
    int jtg = (rem >> 9) % 24;
    int mk = rem / 12288;          // (mat*2+split)*4 + kc, 0..15
    int kc = mk & 3;
    int msplit = mk >> 2;          // 0..3
    int mat = msplit >> 1, split = msplit & 1;
    int r = lane & 15, quad = lane >> 4;
    int k = kc * 32 + quad * 8 + t;
    int n = jtg * 16 + r;
    const float* W = (mat ? Whh : Wih) + (size_t)layer * 128 * 384;
    float v = W[(size_t)k * 384 + n];
    __bf16 hi = (__bf16)v;
    Wg[gid] = split ? (__bf16)(v - (float)hi) : hi;
}

// ---------------- readout-weight conversion: hi/lo split -------------------
__global__ __launch_bounds__(256) void k_wrconv(
    const float* __restrict__ Wr1, __bf16* __restrict__ Wr1s)
{
    int gid = blockIdx.x * 256 + threadIdx.x;
    if (gid >= WR_TOTAL) return;
    int t = gid & 7;
    int lane = (gid >> 3) & 63;
    int jtg = (gid >> 9) & 7;
    int kc = (gid >> 12) & 3;
    int split = gid >> 14;
    int r = lane & 15, quad = lane >> 4;
    int k = kc * 32 + quad * 8 + t;
    int n = jtg * 16 + r;
    float v = Wr1[(size_t)k * H + n];
    __bf16 hi = (__bf16)v;
    Wr1s[gid] = split ? (__bf16)(v - (float)hi) : hi;
}

// ---------------- counting sort by key = type*nn + dst ---------------------
__global__ __launch_bounds__(256) void k_hist(
    const int* __restrict__ et, const int* __restrict__ dst,
    int* __restrict__ cnt, int n_edges, int nn)
{
    int i = blockIdx.x * 256 + threadIdx.x;
    if (i < n_edges) atomicAdd(&cnt[et[i] * nn + dst[i]], 1);
}

__global__ __launch_bounds__(1024) void k_scan1(
    const int* __restrict__ cnt, int* __restrict__ bsum, int n)
{
    int i = blockIdx.x * 1024 + threadIdx.x;
    int v = (i < n) ? cnt[i] : 0;
#pragma unroll
    for (int off = 32; off > 0; off >>= 1) v += __shfl_down(v, off, 64);
    __shared__ int ws[16];
    int lane = threadIdx.x & 63, w = threadIdx.x >> 6;
    if (lane == 0) ws[w] = v;
    __syncthreads();
    if (threadIdx.x < 16) {
        int x = ws[threadIdx.x];
#pragma unroll
        for (int off = 8; off > 0; off >>= 1) x += __shfl_down(x, off, 64);
        if (threadIdx.x == 0) bsum[blockIdx.x] = x;
    }
}

__global__ __launch_bounds__(128) void k_scan2(
    int* __restrict__ bsum, int* __restrict__ offs, int nb, int n)
{
    int lane = threadIdx.x & 63, w = threadIdx.x >> 6;
    int v = (threadIdx.x < nb) ? bsum[threadIdx.x] : 0;
    int orig = v;
#pragma unroll
    for (int off = 1; off < 64; off <<= 1) {
        int t = __shfl_up(v, off, 64);
        if (lane >= off) v += t;
    }
    __shared__ int w0sum;
    if (threadIdx.x == 63) w0sum = v;
    __syncthreads();
    int ex = v - orig + (w ? w0sum : 0);
    if (threadIdx.x < nb) bsum[threadIdx.x] = ex;
    if (threadIdx.x == nb - 1) offs[n] = ex + orig;
}

__global__ __launch_bounds__(1024) void k_scan3(
    const int* __restrict__ cnt, const int* __restrict__ bsum,
    int* __restrict__ offs, int n)
{
    int i = blockIdx.x * 1024 + threadIdx.x;
    int v = (i < n) ? cnt[i] : 0;
    int orig = v;
    int lane = threadIdx.x & 63, w = threadIdx.x >> 6;
#pragma unroll
    for (int off = 1; off < 64; off <<= 1) {
        int t = __shfl_up(v, off, 64);
        if (lane >= off) v += t;
    }
    __shared__ int ws[16];
    if (lane == 63) ws[w] = v;
    __syncthreads();
    if (threadIdx.x < 16) {
        int x = ws[threadIdx.x];
#pragma unroll
        for (int off = 1; off < 16; off <<= 1) {
            int t = __shfl_up(x, off, 64);
            if (lane >= off) x += t;
        }
        ws[threadIdx.x] = x;
    }
    __syncthreads();
    int wbase = w ? ws[w - 1] : 0;
    if (i < n) offs[i] = bsum[blockIdx.x] + wbase + v - orig;
}

__global__ __launch_bounds__(256) void k_place(
    const int* __restrict__ et, const int* __restrict__ dst,
    const int* __restrict__ offs, int* __restrict__ cnt,
    int* __restrict__ bucket, int n_edges, int nn)
{
    int i = blockIdx.x * 256 + threadIdx.x;
    if (i < n_edges) {
        int key = et[i] * nn + dst[i];
        int p = atomicAdd(&cnt[key], -1) - 1;
        bucket[offs[key] + p] = i;
    }
}

// ---------------- fused MFMA message kernel (exact R9, 89us measured) ------
__global__ __launch_bounds__(512, 4) void k_msg(
    const __bf16* __restrict__ hb,
    const int* __restrict__ bucket, const int* __restrict__ offs,
    const int* __restrict__ src, const int* __restrict__ dst,
    const __bf16* __restrict__ Wsw, const float* __restrict__ b1l,
    const float* __restrict__ b2l,
    float* __restrict__ agg, int n_edges, int nn)
{
    const int t = blockIdx.y;
    const int c0 = offs[nn];
    const int cnt = t ? (n_edges - c0) : c0;
    const int base = t ? c0 : 0;
    const int start = blockIdx.x * TE2;
    if (start >= cnt) return;

    const __bf16* __restrict__ W = Wsw + (size_t)t * 12 * 4096;
    const float*  __restrict__ b1 = b1l + t * H;
    const float*  __restrict__ b2 = b2l + t * H;

    __shared__ __bf16 sW[4096];            // 8 KB weight chunk
    __shared__ float  sMsg[TE2 * MS2];     // 67584 B; sHid aliases per-wave
    __shared__ int    sDstV[TE2];

    const int tid  = threadIdx.x;
    const int lane = tid & 63;
    const int w    = tid >> 6;
    const int r    = lane & 15;
    const int quad = lane >> 4;

    f32x4 wreg[12];
#pragma unroll
    for (int c = 0; c < 12; c++)
        wreg[c] = *(const f32x4*)(W + c * 4096 + tid * 8);

    if (tid < TE2) {
        int i = start + tid;
        sDstV[tid] = (i < cnt) ? dst[bucket[base + i]] : -1;
    }

    int ei = start + w * 16 + r;
    int e = bucket[base + (ei < cnt ? ei : cnt - 1)];
    const __bf16* aps = hb + (size_t)src[e] * H;
    const __bf16* apd = hb + (size_t)dst[e] * H;

    bf16x8 afS[4];
#pragma unroll
    for (int i = 0; i < 4; i++)
        afS[i] = *(const bf16x8*)(aps + i * 32 + quad * 8);

    __syncthreads();

    // ---- Phase A: hidT = (cat @ W1)^T, K=256 in 8 chunks ----
    f32x4 acc[8];
#pragma unroll
    for (int ct = 0; ct < 8; ct++) acc[ct] = (f32x4){0.f, 0.f, 0.f, 0.f};

    bf16x8 afD[4];
#pragma unroll
    for (int kc = 0; kc < 8; kc++) {
        __syncthreads();
        *(f32x4*)(sW + tid * 8) = wreg[kc];
        __syncthreads();
        if (kc == 2) {
#pragma unroll
            for (int i = 0; i < 4; i++)
                afD[i] = *(const bf16x8*)(apd + i * 32 + quad * 8);
        }
        bf16x8 b = (kc < 4) ? afS[kc] : afD[kc - 4];
#pragma unroll
        for (int ct = 0; ct < 8; ct++) {
            bf16x8 a = *(const bf16x8*)(sW + ct * 512 + lane * 8);
            acc[ct] = __builtin_amdgcn_mfma_f32_16x16x32_bf16(a, b, acc[ct], 0, 0, 0);
        }
    }

    // epilogue A: bias + relu -> bf16 -> sHid[edge=r][feat] (own-wave strip)
    __bf16* sHid = (__bf16*)(sMsg + w * 16 * MS2);   // 16 rows x HS stride
#pragma unroll
    for (int ct = 0; ct < 8; ct++) {
        f32x4 bb4 = *(const f32x4*)(b1 + ct * 16 + quad * 4);
        bf16x4 hv;
#pragma unroll
        for (int g = 0; g < 4; g++)
            hv[g] = (__bf16)fmaxf(acc[ct][g] + bb4[g], 0.f);
        *(bf16x4*)(sHid + r * HS + ct * 16 + quad * 4) = hv;
    }

    // ---- Phase B: msgT = (hid @ W2)^T, K=128 in 4 chunks ----
    f32x4 acc2[8];
#pragma unroll
    for (int ct = 0; ct < 8; ct++) acc2[ct] = (f32x4){0.f, 0.f, 0.f, 0.f};
#pragma unroll
    for (int kc = 0; kc < 4; kc++) {
        __syncthreads();
        *(f32x4*)(sW + tid * 8) = wreg[8 + kc];
        __syncthreads();
        bf16x8 b = *(const bf16x8*)(sHid + r * HS + kc * 32 + quad * 8);
#pragma unroll
        for (int ct = 0; ct < 8; ct++) {
            bf16x8 a = *(const bf16x8*)(sW + ct * 512 + lane * 8);
            acc2[ct] = __builtin_amdgcn_mfma_f32_16x16x32_bf16(a, b, acc2[ct], 0, 0, 0);
        }
    }

    // ---- Phase C: msgs (+bias) -> sMsg[edge = 16w+r][feat], vectorized ----
#pragma unroll
    for (int ct = 0; ct < 8; ct++) {
        f32x4 bb4 = *(const f32x4*)(b2 + ct * 16 + quad * 4);
        f32x4 mv;
#pragma unroll
        for (int g = 0; g < 4; g++)
            mv[g] = acc2[ct][g] + bb4[g];
        *(f32x4*)(sMsg + (w * 16 + r) * MS2 + ct * 16 + quad * 4) = mv;
    }
    __syncthreads();

    // segmented reduction over dst-sorted rows; one atomic per run per col
    {
        int j = tid & 127, strip = tid >> 7;
        int e0 = strip * 32;
        float run = 0.f; int curd = -1;
        for (int q = 0; q < 32; q++) {
            int d = sDstV[e0 + q];
            float v = sMsg[(e0 + q) * MS2 + j];
            if (d != curd) {
                if (curd >= 0) atomicAdd(agg + (size_t)curd * H + j, run);
                run = 0.f; curd = d;
            }
            if (d >= 0) run += v;
        }
        if (curd >= 0) atomicAdd(agg + (size_t)curd * H + j, run);
    }
}

// ---------------- GRU cell: split-precision MFMA, mat-specialized waves ----
// 32 nodes/block, 1024 thr (16 waves). Wave w: mat = w>>3 (0=Wih/agg,
// 1=Whh/h), jt = w&7. Per wave: acc[2][3], B[2][6] double-buffer, A[2][2].
// mat-1 waves pass gate accs to mat-0 waves via LDS (aliases dead sIn).
// Accumulation order identical to R13 => bit-identical output.
// Also zeroes agg (for the next layer) after reading it.
__global__ __launch_bounds__(1024, 4) void k_gru(
    float* __restrict__ h, __bf16* __restrict__ hb,
    float* __restrict__ agg,
    const __bf16* __restrict__ Wg,
    const float* __restrict__ bih, const float* __restrict__ bhh,
    int n_nodes)
{
    const int nb = blockIdx.x * 32;
    const int tid = threadIdx.x;

    // phase 1: sIn[4][32][HS] bf16 (34816 B); phase 2: sEx[3][32][EXS] f32
    __shared__ char sRaw[3 * 32 * EXS * 4];          // 50688 B
    __bf16 (*sIn)[32][HS] = (__bf16(*)[32][HS])sRaw;
    float* sEx = (float*)sRaw;

    {   // stage + split inputs: one float4 of agg + h per thread; zero agg
        int e = tid >> 5, c4 = (tid & 31) * 4;
        int n = nb + e;
        float4 av = {0.f, 0.f, 0.f, 0.f}, hv = {0.f, 0.f, 0.f, 0.f};
        if (n < n_nodes) {
            av = *(const float4*)(agg + (size_t)n * H + c4);
            hv = *(const float4*)(h + (size_t)n * H + c4);
            float4 z = {0.f, 0.f, 0.f, 0.f};
            *(float4*)(agg + (size_t)n * H + c4) = z;   // ready for next layer
        }
        bf16x4 ahi, alo, hhi, hlo;
        float af[4] = {av.x, av.y, av.z, av.w};
        float hf[4] = {hv.x, hv.y, hv.z, hv.w};
#pragma unroll
        for (int c = 0; c < 4; c++) {
            __bf16 ah = (__bf16)af[c]; ahi[c] = ah; alo[c] = (__bf16)(af[c] - (float)ah);
            __bf16 hh = (__bf16)hf[c]; hhi[c] = hh; hlo[c] = (__bf16)(hf[c] - (float)hh);
        }
        *(bf16x4*)&sIn[0][e][c4] = ahi;
        *(bf16x4*)&sIn[1][e][c4] = alo;
        *(bf16x4*)&sIn[2][e][c4] = hhi;
        *(bf16x4*)&sIn[3][e][c4] = hlo;
    }
    __syncthreads();

    const int lane = tid & 63, w = tid >> 6;     // w: 0..15
    const int r = lane & 15, quad = lane >> 4;
    const int jt = w & 7;
    const int mat = w >> 3;

    f32x4 acc[2][3];                     // [m][gate]
#pragma unroll
    for (int m = 0; m < 2; m++)
#pragma unroll
        for (int g = 0; g < 3; g++)
            acc[m][g] = (f32x4){0.f, 0.f, 0.f, 0.f};

    bf16x8 B[2][6];                      // [buf][g*2+split]
#pragma unroll
    for (int g = 0; g < 3; g++)
#pragma unroll
    for (int sp = 0; sp < 2; sp++)
        B[0][g * 2 + sp] = *(const bf16x8*)(Wg +
            ((((size_t)(mat * 2 + sp) * 4 + 0) * 24 + (g * 8 + jt)) * 64 + lane) * 8);

#pragma unroll
    for (int kc = 0; kc < 4; kc++) {
        const int cur = kc & 1, nxt = cur ^ 1;
        if (kc < 3) {
#pragma unroll
            for (int g = 0; g < 3; g++)
#pragma unroll
            for (int sp = 0; sp < 2; sp++)
                B[nxt][g * 2 + sp] = *(const bf16x8*)(Wg +
                    ((((size_t)(mat * 2 + sp) * 4 + (kc + 1)) * 24 + (g * 8 + jt)) * 64 + lane) * 8);
        }
        bf16x8 A[2][2];
#pragma unroll
        for (int m = 0; m < 2; m++)
#pragma unroll
            for (int s = 0; s < 2; s++)
                A[m][s] = *(const bf16x8*)&sIn[mat * 2 + s][m * 16 + r][kc * 32 + quad * 8];
#pragma unroll
        for (int g = 0; g < 3; g++) {
            bf16x8 bhi = B[cur][g * 2 + 0];
            bf16x8 blo = B[cur][g * 2 + 1];
#pragma unroll
            for (int m = 0; m < 2; m++) {
                acc[m][g] = __builtin_amdgcn_mfma_f32_16x16x32_bf16(
                    A[m][0], bhi, acc[m][g], 0, 0, 0);
                acc[m][g] = __builtin_amdgcn_mfma_f32_16x16x32_bf16(
                    A[m][0], blo, acc[m][g], 0, 0, 0);
                acc[m][g] = __builtin_amdgcn_mfma_f32_16x16x32_bf16(
                    A[m][1], bhi, acc[m][g], 0, 0, 0);
            }
        }
    }

    __syncthreads();   // all sIn reads done before sEx overwrites

    const int jcol = jt * 16 + r;
    if (mat == 1) {    // publish recurrent-gate accs
#pragma unroll
        for (int m = 0; m < 2; m++)
#pragma unroll
        for (int g = 0; g < 3; g++)
#pragma unroll
        for (int g4 = 0; g4 < 4; g4++) {
            int e = m * 16 + quad * 4 + g4;
            sEx[(g * 32 + e) * EXS + jcol] = acc[m][g][g4];
        }
    }
    __syncthreads();

    if (mat == 0) {    // gate epilogue
        float br_ = bih[jcol], bz_ = bih[128 + jcol], bn_ = bih[256 + jcol];
        float cr = bhh[jcol], cz = bhh[128 + jcol], cn = bhh[256 + jcol];
#pragma unroll
        for (int m = 0; m < 2; m++)
#pragma unroll
        for (int g4 = 0; g4 < 4; g4++) {
            int e = m * 16 + quad * 4 + g4;
            int n = nb + e;
            if (n < n_nodes) {
                float ir = acc[m][0][g4], iz = acc[m][1][g4], in_ = acc[m][2][g4];
                float hr = sEx[(0 * 32 + e) * EXS + jcol];
                float hz = sEx[(1 * 32 + e) * EXS + jcol];
                float hn = sEx[(2 * 32 + e) * EXS + jcol];
                float hold = h[(size_t)n * H + jcol];
                float rr = 1.f / (1.f + expf(-(ir + br_ + hr + cr)));
                float zz = 1.f / (1.f + expf(-(iz + bz_ + hz + cz)));
                float nv = tanhf(in_ + bn_ + rr * (hn + cn));
                float out = (1.f - zz) * nv + zz * hold;
                h[(size_t)n * H + jcol] = out;
                hb[(size_t)n * H + jcol] = (__bf16)out;
            }
        }
    }
}

// ---------------- readout: split-precision MFMA ----------------------------
__global__ __launch_bounds__(256, 4) void k_readout(
    const float* __restrict__ h, const __bf16* __restrict__ Wr1s,
    const float* __restrict__ br1, const float* __restrict__ Wr2,
    const float* __restrict__ br2, float* __restrict__ out, int n_out)
{
    const int nb = blockIdx.x * 32;
    const int tid = threadIdx.x;
    __shared__ __bf16 sIn[2][32][HS];   // h hi/lo (17.4 KB)
    __shared__ float sRed[4][32];

#pragma unroll
    for (int v = 0; v < 4; v++) {
        int idx = tid + 256 * v;            // float4 id, 1024 total
        int e = idx >> 5, c4 = (idx & 31) * 4;
        int n = nb + e;
        float4 hv = {0.f, 0.f, 0.f, 0.f};
        if (n < n_out)
            hv = *(const float4*)(h + (size_t)n * H + c4);
        float hf[4] = {hv.x, hv.y, hv.z, hv.w};
        bf16x4 hhi, hlo;
#pragma unroll
        for (int c = 0; c < 4; c++) {
            __bf16 hh = (__bf16)hf[c];
            hhi[c] = hh; hlo[c] = (__bf16)(hf[c] - (float)hh);
        }
        *(bf16x4*)&sIn[0][e][c4] = hhi;
        *(bf16x4*)&sIn[1][e][c4] = hlo;
    }
    __syncthreads();

    const int lane = tid & 63, w = tid >> 6;
    const int r = lane & 15, quad = lane >> 4;

    f32x4 acc[2][2];                 // [m][j]
#pragma unroll
    for (int m = 0; m < 2; m++)
#pragma unroll
        for (int j = 0; j < 2; j++)
            acc[m][j] = (f32x4){0.f, 0.f, 0.f, 0.f};

#pragma unroll
    for (int kc = 0; kc < 4; kc++) {
        bf16x8 A[2][2];
#pragma unroll
        for (int m = 0; m < 2; m++)
#pragma unroll
            for (int s = 0; s < 2; s++)
                A[m][s] = *(const bf16x8*)&sIn[s][m * 16 + r][kc * 32 + quad * 8];
#pragma unroll
        for (int j = 0; j < 2; j++) {
            int jtg = w * 2 + j;
            bf16x8 bhi = *(const bf16x8*)(Wr1s +
                ((size_t)(0 * 4 + kc) * 8 + jtg) * 512 + lane * 8);
            bf16x8 blo = *(const bf16x8*)(Wr1s +
                ((size_t)(1 * 4 + kc) * 8 + jtg) * 512 + lane * 8);
#pragma unroll
            for (int m = 0; m < 2; m++) {
                acc[m][j] = __builtin_amdgcn_mfma_f32_16x16x32_bf16(
                    A[m][0], bhi, acc[m][j], 0, 0, 0);
                acc[m][j] = __builtin_amdgcn_mfma_f32_16x16x32_bf16(
                    A[m][0], blo, acc[m][j], 0, 0, 0);
                acc[m][j] = __builtin_amdgcn_mfma_f32_16x16x32_bf16(
                    A[m][1], bhi, acc[m][j], 0, 0, 0);
            }
        }
    }

    float part[2][4];
#pragma unroll
    for (int m = 0; m < 2; m++)
#pragma unroll
        for (int g = 0; g < 4; g++) part[m][g] = 0.f;
#pragma unroll
    for (int j = 0; j < 2; j++) {
        int col = (w * 2 + j) * 16 + r;
        float b1v = br1[col], w2v = Wr2[col];
#pragma unroll
        for (int m = 0; m < 2; m++)
#pragma unroll
            for (int g = 0; g < 4; g++)
                part[m][g] += fmaxf(acc[m][j][g] + b1v, 0.f) * w2v;
    }
#pragma unroll
    for (int mask = 1; mask < 16; mask <<= 1)
#pragma unroll
        for (int m = 0; m < 2; m++)
#pragma unroll
            for (int g = 0; g < 4; g++)
                part[m][g] += __shfl_xor(part[m][g], mask, 16);
    if (r == 0) {
#pragma unroll
        for (int m = 0; m < 2; m++)
#pragma unroll
            for (int g = 0; g < 4; g++)
                sRed[w][m * 16 + quad * 4 + g] = part[m][g];
    }
    __syncthreads();
    if (tid < 32) {
        int n = nb + tid;
        if (n < n_out)
            out[n] = sRed[0][tid] + sRed[1][tid] + sRed[2][tid] + sRed[3][tid]
                     + br2[0];
    }
}

// ---------------------------------------------------------------------------
extern "C" void kernel_launch(void* const* d_in, const int* in_sizes, int n_in,
                              void* d_out, int out_size, void* d_ws, size_t ws_size,
                              hipStream_t stream)
{
    const float* x      = (const float*)d_in[0];
    const int*   eidx   = (const int*)d_in[1];
    const int*   etype  = (const int*)d_in[2];
    const float* Win    = (const float*)d_in[4];
    const float* bin    = (const float*)d_in[5];
    const float* W1     = (const float*)d_in[6];   // (3,2,256,128)
    const float* b1     = (const float*)d_in[7];   // (3,2,128)
    const float* W2     = (const float*)d_in[8];   // (3,2,128,128)
    const float* b2     = (const float*)d_in[9];   // (3,2,128)
    const float* Wih    = (const float*)d_in[10];  // (3,128,384)
    const float* bih    = (const float*)d_in[11];  // (3,384)
    const float* Whh    = (const float*)d_in[12];  // (3,128,384)
    const float* bhh    = (const float*)d_in[13];  // (3,384)
    const float* Wr1    = (const float*)d_in[14];
    const float* br1    = (const float*)d_in[15];
    const float* Wr2    = (const float*)d_in[16];
    const float* br2    = (const float*)d_in[17];

    const int n_nodes = in_sizes[0] / FEAT;
    const int n_edges = in_sizes[1] / 2;
    const int L = 3;
    const size_t nh = (size_t)n_nodes * H;

    const int* src = eidx;
    const int* dst = eidx + n_edges;

    // workspace carve-up
    float*  h    = (float*)d_ws;                    // 25.6 MB
    float*  agg  = h + nh;                          // 25.6 MB
    __bf16* hb   = (__bf16*)(agg + nh);             // 12.8 MB
    __bf16* Wsw  = hb + nh;                         // 6*12*4096 bf16
    __bf16* Wg   = Wsw + 6 * 12 * 4096;             // 3*WG_PER_LAYER bf16
    __bf16* Wr1s = Wg + 3 * WG_PER_LAYER;           // WR_TOTAL bf16
    int* bucket  = (int*)(Wr1s + WR_TOTAL);         // n_edges
    int* cnt     = bucket + n_edges;                // 2*nn (also k_place cursors)
    int* offs    = cnt + 2 * n_nodes;               // 2*nn + 1
    int* bsum    = offs + 2 * n_nodes + 1;          // scan block sums

    const int nscan = 2 * n_nodes;
    const int nb = (nscan + 1023) / 1024;

    hipMemsetAsync(cnt, 0, (size_t)nscan * sizeof(int), stream);

    k_wconv<<<(6 * 12 * 4096 + 255) / 256, 256, 0, stream>>>(W1, W2, Wsw);
    k_wgconv<<<(3 * WG_PER_LAYER + 255) / 256, 256, 0, stream>>>(Wih, Whh, Wg);
    k_wrconv<<<(WR_TOTAL + 255) / 256, 256, 0, stream>>>(Wr1, Wr1s);
    k_input<<<((int)nh + 255) / 256, 256, 0, stream>>>(x, Win, bin, h, hb, n_nodes);

    const int eb = (n_edges + 255) / 256;
    k_hist <<<eb, 256, 0, stream>>>(etype, dst, cnt, n_edges, n_nodes);
    k_scan1<<<nb, 1024, 0, stream>>>(cnt, bsum, nscan);
    k_scan2<<<1, 128, 0, stream>>>(bsum, offs, nb, nscan);
    k_scan3<<<nb, 1024, 0, stream>>>(cnt, bsum, offs, nscan);
    k_place<<<eb, 256, 0, stream>>>(etype, dst, offs, cnt, bucket, n_edges, n_nodes);

    // agg zeroed once here; k_gru re-zeroes it for the following layer
    hipMemsetAsync(agg, 0, nh * sizeof(float), stream);

    const dim3 mgrid((n_edges + TE2 - 1) / TE2, 2);
    for (int l = 0; l < L; l++) {
        k_msg<<<mgrid, 512, 0, stream>>>(
            hb, bucket, offs, src, dst,
            Wsw + (size_t)l * 2 * 12 * 4096,
            b1 + (size_t)l * 2 * H, b2 + (size_t)l * 2 * H,
            agg, n_edges, n_nodes);
        k_gru<<<(n_nodes + 31) / 32, 1024, 0, stream>>>(
            h, hb, agg,
            Wg + (size_t)l * WG_PER_LAYER,
            bih + (size_t)l * 384, bhh + (size_t)l * 384,
            n_nodes);
    }

    k_readout<<<(out_size + 31) / 32, 256, 0, stream>>>(
        h, Wr1s, br1, Wr2, br2, (float*)d_out, out_size);
}

// Round 15
// 549.658 us; speedup vs baseline: 1.2713x; 1.0351x over previous
//
#include <hip/hip_runtime.h>
#include <math.h>

// ---------------------------------------------------------------------------
// TannerGNN. Round 15: overhead consolidation. k_prep fuses all weight
// conversions + cnt zeroing + input projection + agg zeroing (6 dispatches
// -> 1, both memsets gone). Last-layer k_gru skips dead hb write + agg
// re-zero. 21 -> 12 dispatches. No math-order changes => absmax must stay
// exactly 0.02734375. k_msg = exact R9 core; k_gru = R14; readout = R13.
// N_NODES=50000, N_EDGES=400000, H=128, L=3, T=2, FEAT=4, N_DATA=40000.
// ---------------------------------------------------------------------------

#define H 128
#define TE2 128        // edges per message block
#define MS2 132        // sMsg row stride in f32
#define HS  136        // sHid/sIn row stride in bf16
#define EXS 132        // sEx row stride in f32 (2-way banks)
#define FEAT 4
#define WG_PER_LAYER 196608   // 2 mat * 2 split * 4 kc * 24 jtg * 64 lane * 8
#define WR_TOTAL 32768        // 2 split * 4 kc * 8 jtg * 64 lane * 8
#define WC_TOTAL 294912       // 6 lt * 12 chunk * 4096

typedef __bf16 bf16x8 __attribute__((ext_vector_type(8)));
typedef __bf16 bf16x4 __attribute__((ext_vector_type(4)));
typedef float  f32x4  __attribute__((ext_vector_type(4)));

// ---------------- mega-prep: weight swizzles + cnt zero + input proj -------
// gid ranges: [0,N1) msg-weight conv; [N1,N1+N2) GRU-weight conv;
// [.., +N3) readout-weight conv; [.., +N4) cnt zero; [.., +N5) input
// projection h/hb + agg zero.
__global__ __launch_bounds__(256) void k_prep(
    const float* __restrict__ W1, const float* __restrict__ W2,
    const float* __restrict__ Wih, const float* __restrict__ Whh,
    const float* __restrict__ Wr1,
    const float* __restrict__ x, const float* __restrict__ Win,
    const float* __restrict__ bin,
    __bf16* __restrict__ Wsw, __bf16* __restrict__ Wg,
    __bf16* __restrict__ Wr1s, int* __restrict__ cnt,
    float* __restrict__ h, __bf16* __restrict__ hb,
    float* __restrict__ agg, int n_nodes)
{
    const int N1 = WC_TOTAL;
    const int N2 = 3 * WG_PER_LAYER;
    const int N3 = WR_TOTAL;
    const int N4 = 2 * n_nodes;
    const long long N5 = (long long)n_nodes * H;
    long long gid = (long long)blockIdx.x * 256 + threadIdx.x;

    if (gid < N1) {
        int g = (int)gid;
        const int per_lt = 12 * 4096;
        int lt = g / per_lt, rem = g % per_lt;
        int chunk = rem >> 12;
        int within = rem & 4095;
        int ct = within >> 9;
        int lane = (within >> 3) & 63;
        int j = within & 7;
        int r = lane & 15, quad = lane >> 4;
        int n = ct * 16 + r;
        float v;
        if (chunk < 8) {
            int k = chunk * 32 + quad * 8 + j;
            v = W1[((size_t)lt * 256 + k) * 128 + n];
        } else {
            int k = (chunk - 8) * 32 + quad * 8 + j;
            v = W2[((size_t)lt * 128 + k) * 128 + n];
        }
        Wsw[g] = (__bf16)v;
        return;
    }
    gid -= N1;
    if (gid < N2) {
        int g = (int)gid;
        int layer = g / WG_PER_LAYER, rem = g % WG_PER_LAYER;
        int t = rem & 7;
        int lane = (rem >> 3) & 63;
        int jtg = (rem >> 9) % 24;
        int mk = rem / 12288;          // (mat*2+split)*4 + kc
        int kc = mk & 3;
        int msplit = mk >> 2;
        int mat = msplit >> 1, split = msplit & 1;
        int r = lane & 15, quad = lane >> 4;
        int k = kc * 32 + quad * 8 + t;
        int n = jtg * 16 + r;
        const float* W = (mat ? Whh : Wih) + (size_t)layer * 128 * 384;
        float v = W[(size_t)k * 384 + n];
        __bf16 hi = (__bf16)v;
        Wg[g] = split ? (__bf16)(v - (float)hi) : hi;
        return;
    }
    gid -= N2;
    if (gid < N3) {
        int g = (int)gid;
        int t = g & 7;
        int lane = (g >> 3) & 63;
        int jtg = (g >> 9) & 7;
        int kc = (g >> 12) & 3;
        int split = g >> 14;
        int r = lane & 15, quad = lane >> 4;
        int k = kc * 32 + quad * 8 + t;
        int n = jtg * 16 + r;
        float v = Wr1[(size_t)k * H + n];
        __bf16 hi = (__bf16)v;
        Wr1s[g] = split ? (__bf16)(v - (float)hi) : hi;
        return;
    }
    gid -= N3;
    if (gid < N4) {
        cnt[(int)gid] = 0;
        return;
    }
    gid -= N4;
    if (gid < N5) {
        int idx = (int)gid;
        int n = idx >> 7, j = idx & 127;
        float acc = bin[j];
#pragma unroll
        for (int f = 0; f < FEAT; f++)
            acc += x[n * FEAT + f] * Win[f * H + j];
        float v = fmaxf(acc, 0.f);
        h[idx] = v;
        hb[idx] = (__bf16)v;
        agg[idx] = 0.f;
    }
}

// ---------------- counting sort by key = type*nn + dst ---------------------
__global__ __launch_bounds__(256) void k_hist(
    const int* __restrict__ et, const int* __restrict__ dst,
    int* __restrict__ cnt, int n_edges, int nn)
{
    int i = blockIdx.x * 256 + threadIdx.x;
    if (i < n_edges) atomicAdd(&cnt[et[i] * nn + dst[i]], 1);
}

__global__ __launch_bounds__(1024) void k_scan1(
    const int* __restrict__ cnt, int* __restrict__ bsum, int n)
{
    int i = blockIdx.x * 1024 + threadIdx.x;
    int v = (i < n) ? cnt[i] : 0;
#pragma unroll
    for (int off = 32; off > 0; off >>= 1) v += __shfl_down(v, off, 64);
    __shared__ int ws[16];
    int lane = threadIdx.x & 63, w = threadIdx.x >> 6;
    if (lane == 0) ws[w] = v;
    __syncthreads();
    if (threadIdx.x < 16) {
        int x = ws[threadIdx.x];
#pragma unroll
        for (int off = 8; off > 0; off >>= 1) x += __shfl_down(x, off, 64);
        if (threadIdx.x == 0) bsum[blockIdx.x] = x;
    }
}

__global__ __launch_bounds__(128) void k_scan2(
    int* __restrict__ bsum, int* __restrict__ offs, int nb, int n)
{
    int lane = threadIdx.x & 63, w = threadIdx.x >> 6;
    int v = (threadIdx.x < nb) ? bsum[threadIdx.x] : 0;
    int orig = v;
#pragma unroll
    for (int off = 1; off < 64; off <<= 1) {
        int t = __shfl_up(v, off, 64);
        if (lane >= off) v += t;
    }
    __shared__ int w0sum;
    if (threadIdx.x == 63) w0sum = v;
    __syncthreads();
    int ex = v - orig + (w ? w0sum : 0);
    if (threadIdx.x < nb) bsum[threadIdx.x] = ex;
    if (threadIdx.x == nb - 1) offs[n] = ex + orig;
}

__global__ __launch_bounds__(1024) void k_scan3(
    const int* __restrict__ cnt, const int* __restrict__ bsum,
    int* __restrict__ offs, int n)
{
    int i = blockIdx.x * 1024 + threadIdx.x;
    int v = (i < n) ? cnt[i] : 0;
    int orig = v;
    int lane = threadIdx.x & 63, w = threadIdx.x >> 6;
#pragma unroll
    for (int off = 1; off < 64; off <<= 1) {
        int t = __shfl_up(v, off, 64);
        if (lane >= off) v += t;
    }
    __shared__ int ws[16];
    if (lane == 63) ws[w] = v;
    __syncthreads();
    if (threadIdx.x < 16) {
        int x = ws[threadIdx.x];
#pragma unroll
        for (int off = 1; off < 16; off <<= 1) {
            int t = __shfl_up(x, off, 64);
            if (lane >= off) x += t;
        }
        ws[threadIdx.x] = x;
    }
    __syncthreads();
    int wbase = w ? ws[w - 1] : 0;
    if (i < n) offs[i] = bsum[blockIdx.x] + wbase + v - orig;
}

__global__ __launch_bounds__(256) void k_place(
    const int* __restrict__ et, const int* __restrict__ dst,
    const int* __restrict__ offs, int* __restrict__ cnt,
    int* __restrict__ bucket, int n_edges, int nn)
{
    int i = blockIdx.x * 256 + threadIdx.x;
    if (i < n_edges) {
        int key = et[i] * nn + dst[i];
        int p = atomicAdd(&cnt[key], -1) - 1;
        bucket[offs[key] + p] = i;
    }
}

// ---------------- fused MFMA message kernel (exact R9, 89us measured) ------
__global__ __launch_bounds__(512, 4) void k_msg(
    const __bf16* __restrict__ hb,
    const int* __restrict__ bucket, const int* __restrict__ offs,
    const int* __restrict__ src, const int* __restrict__ dst,
    const __bf16* __restrict__ Wsw, const float* __restrict__ b1l,
    const float* __restrict__ b2l,
    float* __restrict__ agg, int n_edges, int nn)
{
    const int t = blockIdx.y;
    const int c0 = offs[nn];
    const int cnt = t ? (n_edges - c0) : c0;
    const int base = t ? c0 : 0;
    const int start = blockIdx.x * TE2;
    if (start >= cnt) return;

    const __bf16* __restrict__ W = Wsw + (size_t)t * 12 * 4096;
    const float*  __restrict__ b1 = b1l + t * H;
    const float*  __restrict__ b2 = b2l + t * H;

    __shared__ __bf16 sW[4096];            // 8 KB weight chunk
    __shared__ float  sMsg[TE2 * MS2];     // 67584 B; sHid aliases per-wave
    __shared__ int    sDstV[TE2];

    const int tid  = threadIdx.x;
    const int lane = tid & 63;
    const int w    = tid >> 6;
    const int r    = lane & 15;
    const int quad = lane >> 4;

    f32x4 wreg[12];
#pragma unroll
    for (int c = 0; c < 12; c++)
        wreg[c] = *(const f32x4*)(W + c * 4096 + tid * 8);

    if (tid < TE2) {
        int i = start + tid;
        sDstV[tid] = (i < cnt) ? dst[bucket[base + i]] : -1;
    }

    int ei = start + w * 16 + r;
    int e = bucket[base + (ei < cnt ? ei : cnt - 1)];
    const __bf16* aps = hb + (size_t)src[e] * H;
    const __bf16* apd = hb + (size_t)dst[e] * H;

    bf16x8 afS[4];
#pragma unroll
    for (int i = 0; i < 4; i++)
        afS[i] = *(const bf16x8*)(aps + i * 32 + quad * 8);

    __syncthreads();

    // ---- Phase A: hidT = (cat @ W1)^T, K=256 in 8 chunks ----
    f32x4 acc[8];
#pragma unroll
    for (int ct = 0; ct < 8; ct++) acc[ct] = (f32x4){0.f, 0.f, 0.f, 0.f};

    bf16x8 afD[4];
#pragma unroll
    for (int kc = 0; kc < 8; kc++) {
        __syncthreads();
        *(f32x4*)(sW + tid * 8) = wreg[kc];
        __syncthreads();
        if (kc == 2) {
#pragma unroll
            for (int i = 0; i < 4; i++)
                afD[i] = *(const bf16x8*)(apd + i * 32 + quad * 8);
        }
        bf16x8 b = (kc < 4) ? afS[kc] : afD[kc - 4];
#pragma unroll
        for (int ct = 0; ct < 8; ct++) {
            bf16x8 a = *(const bf16x8*)(sW + ct * 512 + lane * 8);
            acc[ct] = __builtin_amdgcn_mfma_f32_16x16x32_bf16(a, b, acc[ct], 0, 0, 0);
        }
    }

    // epilogue A: bias + relu -> bf16 -> sHid[edge=r][feat] (own-wave strip)
    __bf16* sHid = (__bf16*)(sMsg + w * 16 * MS2);   // 16 rows x HS stride
#pragma unroll
    for (int ct = 0; ct < 8; ct++) {
        f32x4 bb4 = *(const f32x4*)(b1 + ct * 16 + quad * 4);
        bf16x4 hv;
#pragma unroll
        for (int g = 0; g < 4; g++)
            hv[g] = (__bf16)fmaxf(acc[ct][g] + bb4[g], 0.f);
        *(bf16x4*)(sHid + r * HS + ct * 16 + quad * 4) = hv;
    }

    // ---- Phase B: msgT = (hid @ W2)^T, K=128 in 4 chunks ----
    f32x4 acc2[8];
#pragma unroll
    for (int ct = 0; ct < 8; ct++) acc2[ct] = (f32x4){0.f, 0.f, 0.f, 0.f};
#pragma unroll
    for (int kc = 0; kc < 4; kc++) {
        __syncthreads();
        *(f32x4*)(sW + tid * 8) = wreg[8 + kc];
        __syncthreads();
        bf16x8 b = *(const bf16x8*)(sHid + r * HS + kc * 32 + quad * 8);
#pragma unroll
        for (int ct = 0; ct < 8; ct++) {
            bf16x8 a = *(const bf16x8*)(sW + ct * 512 + lane * 8);
            acc2[ct] = __builtin_amdgcn_mfma_f32_16x16x32_bf16(a, b, acc2[ct], 0, 0, 0);
        }
    }

    // ---- Phase C: msgs (+bias) -> sMsg[edge = 16w+r][feat], vectorized ----
#pragma unroll
    for (int ct = 0; ct < 8; ct++) {
        f32x4 bb4 = *(const f32x4*)(b2 + ct * 16 + quad * 4);
        f32x4 mv;
#pragma unroll
        for (int g = 0; g < 4; g++)
            mv[g] = acc2[ct][g] + bb4[g];
        *(f32x4*)(sMsg + (w * 16 + r) * MS2 + ct * 16 + quad * 4) = mv;
    }
    __syncthreads();

    // segmented reduction over dst-sorted rows; one atomic per run per col
    {
        int j = tid & 127, strip = tid >> 7;
        int e0 = strip * 32;
        float run = 0.f; int curd = -1;
        for (int q = 0; q < 32; q++) {
            int d = sDstV[e0 + q];
            float v = sMsg[(e0 + q) * MS2 + j];
            if (d != curd) {
                if (curd >= 0) atomicAdd(agg + (size_t)curd * H + j, run);
                run = 0.f; curd = d;
            }
            if (d >= 0) run += v;
        }
        if (curd >= 0) atomicAdd(agg + (size_t)curd * H + j, run);
    }
}

// ---------------- GRU cell: split-precision MFMA, mat-specialized waves ----
// last=1 (final layer): skip dead hb write and agg re-zero.
__global__ __launch_bounds__(1024, 4) void k_gru(
    float* __restrict__ h, __bf16* __restrict__ hb,
    float* __restrict__ agg,
    const __bf16* __restrict__ Wg,
    const float* __restrict__ bih, const float* __restrict__ bhh,
    int n_nodes, int last)
{
    const int nb = blockIdx.x * 32;
    const int tid = threadIdx.x;

    // phase 1: sIn[4][32][HS] bf16 (34816 B); phase 2: sEx[3][32][EXS] f32
    __shared__ char sRaw[3 * 32 * EXS * 4];          // 50688 B
    __bf16 (*sIn)[32][HS] = (__bf16(*)[32][HS])sRaw;
    float* sEx = (float*)sRaw;

    {   // stage + split inputs: one float4 of agg + h per thread
        int e = tid >> 5, c4 = (tid & 31) * 4;
        int n = nb + e;
        float4 av = {0.f, 0.f, 0.f, 0.f}, hv = {0.f, 0.f, 0.f, 0.f};
        if (n < n_nodes) {
            av = *(const float4*)(agg + (size_t)n * H + c4);
            hv = *(const float4*)(h + (size_t)n * H + c4);
            if (!last) {
                float4 z = {0.f, 0.f, 0.f, 0.f};
                *(float4*)(agg + (size_t)n * H + c4) = z;  // ready for next layer
            }
        }
        bf16x4 ahi, alo, hhi, hlo;
        float af[4] = {av.x, av.y, av.z, av.w};
        float hf[4] = {hv.x, hv.y, hv.z, hv.w};
#pragma unroll
        for (int c = 0; c < 4; c++) {
            __bf16 ah = (__bf16)af[c]; ahi[c] = ah; alo[c] = (__bf16)(af[c] - (float)ah);
            __bf16 hh = (__bf16)hf[c]; hhi[c] = hh; hlo[c] = (__bf16)(hf[c] - (float)hh);
        }
        *(bf16x4*)&sIn[0][e][c4] = ahi;
        *(bf16x4*)&sIn[1][e][c4] = alo;
        *(bf16x4*)&sIn[2][e][c4] = hhi;
        *(bf16x4*)&sIn[3][e][c4] = hlo;
    }
    __syncthreads();

    const int lane = tid & 63, w = tid >> 6;     // w: 0..15
    const int r = lane & 15, quad = lane >> 4;
    const int jt = w & 7;
    const int mat = w >> 3;

    f32x4 acc[2][3];                     // [m][gate]
#pragma unroll
    for (int m = 0; m < 2; m++)
#pragma unroll
        for (int g = 0; g < 3; g++)
            acc[m][g] = (f32x4){0.f, 0.f, 0.f, 0.f};

    bf16x8 B[2][6];                      // [buf][g*2+split]
#pragma unroll
    for (int g = 0; g < 3; g++)
#pragma unroll
    for (int sp = 0; sp < 2; sp++)
        B[0][g * 2 + sp] = *(const bf16x8*)(Wg +
            ((((size_t)(mat * 2 + sp) * 4 + 0) * 24 + (g * 8 + jt)) * 64 + lane) * 8);

#pragma unroll
    for (int kc = 0; kc < 4; kc++) {
        const int cur = kc & 1, nxt = cur ^ 1;
        if (kc < 3) {
#pragma unroll
            for (int g = 0; g < 3; g++)
#pragma unroll
            for (int sp = 0; sp < 2; sp++)
                B[nxt][g * 2 + sp] = *(const bf16x8*)(Wg +
                    ((((size_t)(mat * 2 + sp) * 4 + (kc + 1)) * 24 + (g * 8 + jt)) * 64 + lane) * 8);
        }
        bf16x8 A[2][2];
#pragma unroll
        for (int m = 0; m < 2; m++)
#pragma unroll
            for (int s = 0; s < 2; s++)
                A[m][s] = *(const bf16x8*)&sIn[mat * 2 + s][m * 16 + r][kc * 32 + quad * 8];
#pragma unroll
        for (int g = 0; g < 3; g++) {
            bf16x8 bhi = B[cur][g * 2 + 0];
            bf16x8 blo = B[cur][g * 2 + 1];
#pragma unroll
            for (int m = 0; m < 2; m++) {
                acc[m][g] = __builtin_amdgcn_mfma_f32_16x16x32_bf16(
                    A[m][0], bhi, acc[m][g], 0, 0, 0);
                acc[m][g] = __builtin_amdgcn_mfma_f32_16x16x32_bf16(
                    A[m][0], blo, acc[m][g], 0, 0, 0);
                acc[m][g] = __builtin_amdgcn_mfma_f32_16x16x32_bf16(
                    A[m][1], bhi, acc[m][g], 0, 0, 0);
            }
        }
    }

    __syncthreads();   // all sIn reads done before sEx overwrites

    const int jcol = jt * 16 + r;
    if (mat == 1) {    // publish recurrent-gate accs
#pragma unroll
        for (int m = 0; m < 2; m++)
#pragma unroll
        for (int g = 0; g < 3; g++)
#pragma unroll
        for (int g4 = 0; g4 < 4; g4++) {
            int e = m * 16 + quad * 4 + g4;
            sEx[(g * 32 + e) * EXS + jcol] = acc[m][g][g4];
        }
    }
    __syncthreads();

    if (mat == 0) {    // gate epilogue
        float br_ = bih[jcol], bz_ = bih[128 + jcol], bn_ = bih[256 + jcol];
        float cr = bhh[jcol], cz = bhh[128 + jcol], cn = bhh[256 + jcol];
#pragma unroll
        for (int m = 0; m < 2; m++)
#pragma unroll
        for (int g4 = 0; g4 < 4; g4++) {
            int e = m * 16 + quad * 4 + g4;
            int n = nb + e;
            if (n < n_nodes) {
                float ir = acc[m][0][g4], iz = acc[m][1][g4], in_ = acc[m][2][g4];
                float hr = sEx[(0 * 32 + e) * EXS + jcol];
                float hz = sEx[(1 * 32 + e) * EXS + jcol];
                float hn = sEx[(2 * 32 + e) * EXS + jcol];
                float hold = h[(size_t)n * H + jcol];
                float rr = 1.f / (1.f + expf(-(ir + br_ + hr + cr)));
                float zz = 1.f / (1.f + expf(-(iz + bz_ + hz + cz)));
                float nv = tanhf(in_ + bn_ + rr * (hn + cn));
                float out = (1.f - zz) * nv + zz * hold;
                h[(size_t)n * H + jcol] = out;
                if (!last) hb[(size_t)n * H + jcol] = (__bf16)out;
            }
        }
    }
}

// ---------------- readout: split-precision MFMA ----------------------------
__global__ __launch_bounds__(256, 4) void k_readout(
    const float* __restrict__ h, const __bf16* __restrict__ Wr1s,
    const float* __restrict__ br1, const float* __restrict__ Wr2,
    const float* __restrict__ br2, float* __restrict__ out, int n_out)
{
    const int nb = blockIdx.x * 32;
    const int tid = threadIdx.x;
    __shared__ __bf16 sIn[2][32][HS];   // h hi/lo (17.4 KB)
    __shared__ float sRed[4][32];

#pragma unroll
    for (int v = 0; v < 4; v++) {
        int idx = tid + 256 * v;            // float4 id, 1024 total
        int e = idx >> 5, c4 = (idx & 31) * 4;
        int n = nb + e;
        float4 hv = {0.f, 0.f, 0.f, 0.f};
        if (n < n_out)
            hv = *(const float4*)(h + (size_t)n * H + c4);
        float hf[4] = {hv.x, hv.y, hv.z, hv.w};
        bf16x4 hhi, hlo;
#pragma unroll
        for (int c = 0; c < 4; c++) {
            __bf16 hh = (__bf16)hf[c];
            hhi[c] = hh; hlo[c] = (__bf16)(hf[c] - (float)hh);
        }
        *(bf16x4*)&sIn[0][e][c4] = hhi;
        *(bf16x4*)&sIn[1][e][c4] = hlo;
    }
    __syncthreads();

    const int lane = tid & 63, w = tid >> 6;
    const int r = lane & 15, quad = lane >> 4;

    f32x4 acc[2][2];                 // [m][j]
#pragma unroll
    for (int m = 0; m < 2; m++)
#pragma unroll
        for (int j = 0; j < 2; j++)
            acc[m][j] = (f32x4){0.f, 0.f, 0.f, 0.f};

#pragma unroll
    for (int kc = 0; kc < 4; kc++) {
        bf16x8 A[2][2];
#pragma unroll
        for (int m = 0; m < 2; m++)
#pragma unroll
            for (int s = 0; s < 2; s++)
                A[m][s] = *(const bf16x8*)&sIn[s][m * 16 + r][kc * 32 + quad * 8];
#pragma unroll
        for (int j = 0; j < 2; j++) {
            int jtg = w * 2 + j;
            bf16x8 bhi = *(const bf16x8*)(Wr1s +
                ((size_t)(0 * 4 + kc) * 8 + jtg) * 512 + lane * 8);
            bf16x8 blo = *(const bf16x8*)(Wr1s +
                ((size_t)(1 * 4 + kc) * 8 + jtg) * 512 + lane * 8);
#pragma unroll
            for (int m = 0; m < 2; m++) {
                acc[m][j] = __builtin_amdgcn_mfma_f32_16x16x32_bf16(
                    A[m][0], bhi, acc[m][j], 0, 0, 0);
                acc[m][j] = __builtin_amdgcn_mfma_f32_16x16x32_bf16(
                    A[m][0], blo, acc[m][j], 0, 0, 0);
                acc[m][j] = __builtin_amdgcn_mfma_f32_16x16x32_bf16(
                    A[m][1], bhi, acc[m][j], 0, 0, 0);
            }
        }
    }

    float part[2][4];
#pragma unroll
    for (int m = 0; m < 2; m++)
#pragma unroll
        for (int g = 0; g < 4; g++) part[m][g] = 0.f;
#pragma unroll
    for (int j = 0; j < 2; j++) {
        int col = (w * 2 + j) * 16 + r;
        float b1v = br1[col], w2v = Wr2[col];
#pragma unroll
        for (int m = 0; m < 2; m++)
#pragma unroll
            for (int g = 0; g < 4; g++)
                part[m][g] += fmaxf(acc[m][j][g] + b1v, 0.f) * w2v;
    }
#pragma unroll
    for (int mask = 1; mask < 16; mask <<= 1)
#pragma unroll
        for (int m = 0; m < 2; m++)
#pragma unroll
            for (int g = 0; g < 4; g++)
                part[m][g] += __shfl_xor(part[m][g], mask, 16);
    if (r == 0) {
#pragma unroll
        for (int m = 0; m < 2; m++)
#pragma unroll
            for (int g = 0; g < 4; g++)
                sRed[w][m * 16 + quad * 4 + g] = part[m][g];
    }
    __syncthreads();
    if (tid < 32) {
        int n = nb + tid;
        if (n < n_out)
            out[n] = sRed[0][tid] + sRed[1][tid] + sRed[2][tid] + sRed[3][tid]
                     + br2[0];
    }
}

// ---------------------------------------------------------------------------
extern "C" void kernel_launch(void* const* d_in, const int* in_sizes, int n_in,
                              void* d_out, int out_size, void* d_ws, size_t ws_size,
                              hipStream_t stream)
{
    const float* x      = (const float*)d_in[0];
    const int*   eidx   = (const int*)d_in[1];
    const int*   etype  = (const int*)d_in[2];
    const float* Win    = (const float*)d_in[4];
    const float* bin    = (const float*)d_in[5];
    const float* W1     = (const float*)d_in[6];   // (3,2,256,128)
    const float* b1     = (const float*)d_in[7];   // (3,2,128)
    const float* W2     = (const float*)d_in[8];   // (3,2,128,128)
    const float* b2     = (const float*)d_in[9];   // (3,2,128)
    const float* Wih    = (const float*)d_in[10];  // (3,128,384)
    const float* bih    = (const float*)d_in[11];  // (3,384)
    const float* Whh    = (const float*)d_in[12];  // (3,128,384)
    const float* bhh    = (const float*)d_in[13];  // (3,384)
    const float* Wr1    = (const float*)d_in[14];
    const float* br1    = (const float*)d_in[15];
    const float* Wr2    = (const float*)d_in[16];
    const float* br2    = (const float*)d_in[17];

    const int n_nodes = in_sizes[0] / FEAT;
    const int n_edges = in_sizes[1] / 2;
    const int L = 3;
    const size_t nh = (size_t)n_nodes * H;

    const int* src = eidx;
    const int* dst = eidx + n_edges;

    // workspace carve-up
    float*  h    = (float*)d_ws;                    // 25.6 MB
    float*  agg  = h + nh;                          // 25.6 MB
    __bf16* hb   = (__bf16*)(agg + nh);             // 12.8 MB
    __bf16* Wsw  = hb + nh;                         // WC_TOTAL bf16
    __bf16* Wg   = Wsw + WC_TOTAL;                  // 3*WG_PER_LAYER bf16
    __bf16* Wr1s = Wg + 3 * WG_PER_LAYER;           // WR_TOTAL bf16
    int* bucket  = (int*)(Wr1s + WR_TOTAL);         // n_edges
    int* cnt     = bucket + n_edges;                // 2*nn (also k_place cursors)
    int* offs    = cnt + 2 * n_nodes;               // 2*nn + 1
    int* bsum    = offs + 2 * n_nodes + 1;          // scan block sums

    const int nscan = 2 * n_nodes;
    const int nb = (nscan + 1023) / 1024;

    // one mega-prep kernel: weight swizzles + cnt zero + input proj + agg 0
    const long long prep_total = (long long)WC_TOTAL + 3 * WG_PER_LAYER
                               + WR_TOTAL + nscan + (long long)nh;
    k_prep<<<(int)((prep_total + 255) / 256), 256, 0, stream>>>(
        W1, W2, Wih, Whh, Wr1, x, Win, bin,
        Wsw, Wg, Wr1s, cnt, h, hb, agg, n_nodes);

    const int eb = (n_edges + 255) / 256;
    k_hist <<<eb, 256, 0, stream>>>(etype, dst, cnt, n_edges, n_nodes);
    k_scan1<<<nb, 1024, 0, stream>>>(cnt, bsum, nscan);
    k_scan2<<<1, 128, 0, stream>>>(bsum, offs, nb, nscan);
    k_scan3<<<nb, 1024, 0, stream>>>(cnt, bsum, offs, nscan);
    k_place<<<eb, 256, 0, stream>>>(etype, dst, offs, cnt, bucket, n_edges, n_nodes);

    const dim3 mgrid((n_edges + TE2 - 1) / TE2, 2);
    for (int l = 0; l < L; l++) {
        k_msg<<<mgrid, 512, 0, stream>>>(
            hb, bucket, offs, src, dst,
            Wsw + (size_t)l * 2 * 12 * 4096,
            b1 + (size_t)l * 2 * H, b2 + (size_t)l * 2 * H,
            agg, n_edges, n_nodes);
        k_gru<<<(n_nodes + 31) / 32, 1024, 0, stream>>>(
            h, hb, agg,
            Wg + (size_t)l * WG_PER_LAYER,
            bih + (size_t)l * 384, bhh + (size_t)l * 384,
            n_nodes, (l == L - 1) ? 1 : 0);
    }

    k_readout<<<(out_size + 31) / 32, 256, 0, stream>>>(
        h, Wr1s, br1, Wr2, br2, (float*)d_out, out_size);
}